// Round 15
// baseline (628.053 us; speedup 1.0000x reference)
//
#include <hip/hip_runtime.h>
#include <cstdint>

// Problem constants
#define NN     20000      // nodes
#define NE     320000     // input edges
#define ETOT   340000     // edges + self loops
#define K1R    3000       // in_dim
#define K1     3072       // padded K for GEMM1
#define NPAD   20224      // 79*256 padded rows (256-tile GEMM1)
#define NCOL1  2048       // 4 x 512 packed outputs (xl_s|xr_s|xl_p|xr_p)
#define LDA2   512        // layer-2 A row (plain bf16)
#define MU_SZ  1280000    // 20000*64

typedef __bf16 bf16x8 __attribute__((ext_vector_type(8)));
typedef float f32x4 __attribute__((ext_vector_type(4)));
typedef unsigned short u16x8 __attribute__((ext_vector_type(8)));

__device__ inline unsigned short f2bf(float f) {
  union { float f; unsigned u; } v; v.f = f;
  unsigned r = v.u + 0x7FFFu + ((v.u >> 16) & 1u);
  return (unsigned short)(r >> 16);
}
__device__ inline float bf2f(unsigned short h) {
  union { unsigned u; float f; } v; v.u = ((unsigned)h) << 16;
  return v.f;
}

typedef const __attribute__((address_space(1))) void* gas1_t;
typedef __attribute__((address_space(3))) void* las3_t;
__device__ inline void llds16(const void* g, void* l) {
  __builtin_amdgcn_global_load_lds((gas1_t)(uintptr_t)g,
                                   (las3_t)(uint32_t)(uintptr_t)l, 16, 0, 0);
}

// ---------------- mega-prep: pack_w1 | count | convert_x in one launch ----------
// NOTE: pack_w2b is NOT fused here — B2s/B2p alias Xb's region and may only be
// written AFTER gemm256 has consumed Xb (R12's fusion corrupted Xb -> absmax 66).
#define PB_PW1  1536                       // pack_w1: 48 x 32 blocks
#define PB_CNT  (PB_PW1 + 1329)            // count: ceil(ETOT/256)
#define PB_CVT  (PB_CNT + 30336)           // convert: NPAD*384/256

__global__ __launch_bounds__(256)
void k_prep(const float* __restrict__ X, unsigned short* __restrict__ Xb,
            const float* __restrict__ W0, const float* __restrict__ W1,
            const float* __restrict__ W2, const float* __restrict__ W3,
            unsigned short* __restrict__ Wp,
            const int* __restrict__ ei, int* __restrict__ counts) {
  __shared__ float tile[64][65];
  int b = blockIdx.x, tid = threadIdx.x;

  if (b < PB_PW1) {
    int k0 = (b % 48) * 64, n0 = (b / 48) * 64;
    int m = n0 >> 9, c0 = n0 & 511;
    const float* W = (m == 0) ? W0 : (m == 1) ? W1 : (m == 2) ? W2 : W3;
    int tx = tid & 63, ty = tid >> 6;
#pragma unroll
    for (int rep = 0; rep < 16; rep++) {
      int i = ty + rep * 4;
      int k = k0 + i;
      tile[i][tx] = (k < K1R) ? W[(size_t)k * 512 + c0 + tx] : 0.f;
    }
    __syncthreads();
#pragma unroll
    for (int rep = 0; rep < 16; rep++) {
      int i = ty + rep * 4;
      Wp[(size_t)(n0 + i) * K1 + k0 + tx] = f2bf(tile[tx][i]);
    }
  } else if (b < PB_CNT) {
    int e = (b - PB_PW1) * 256 + tid;
    if (e < ETOT) {
      int dst = (e < NE) ? ei[NE + e] : (e - NE);
      atomicAdd(&counts[dst], 1);
    }
  } else {
    const int CH = K1 / 8;
    int idx = (b - PB_CNT) * 256 + tid;
    if (idx >= NPAD * CH) return;
    int r = idx / CH, c8 = (idx % CH) * 8;
    u16x8 o;
    if (r < NN && c8 < K1R) {
      const float4* p = (const float4*)(X + (size_t)r * K1R + c8);
      float4 a = p[0], bb = p[1];
      o[0]=f2bf(a.x); o[1]=f2bf(a.y); o[2]=f2bf(a.z); o[3]=f2bf(a.w);
      o[4]=f2bf(bb.x); o[5]=f2bf(bb.y); o[6]=f2bf(bb.z); o[7]=f2bf(bb.w);
    } else {
#pragma unroll
      for (int j = 0; j < 8; j++) o[j] = 0;
    }
    *(u16x8*)(Xb + (size_t)r * K1 + c8) = o;
  }
}

// ---------------- pack layer-2 weights (launched AFTER gemm256; B2 aliases Xb) ----------

__global__ __launch_bounds__(256)
void k_pack_w2b(const float* __restrict__ Wl_s, const float* __restrict__ Wr_s,
                const float* __restrict__ Wl_p, const float* __restrict__ Wr_p,
                unsigned short* __restrict__ B2s, unsigned short* __restrict__ B2p) {
  int gidx = blockIdx.x * 256 + threadIdx.x;   // grid 512 -> 131072
  int br = gidx >> 16, idx = gidx & 65535;
  const float* Wl = br ? Wl_p : Wl_s;
  const float* Wr = br ? Wr_p : Wr_s;
  unsigned short* B2 = br ? B2p : B2s;
  int n = idx >> 9, k = idx & 511;
  float v = (n < 64) ? Wl[(size_t)k * 64 + n] : Wr[(size_t)k * 64 + (n - 64)];
  B2[idx] = f2bf(v);
}

// ---------------- CSR scan + scatter ----------------

__global__ void k_scan(const int* __restrict__ counts, int* __restrict__ row_ptr) {
  __shared__ int part[1024];
  int t = threadIdx.x;
  int base = t * 20;
  int loc[20];
  int s = 0;
#pragma unroll
  for (int i = 0; i < 20; i++) {
    int idx = base + i;
    loc[i] = s;
    s += (idx < NN) ? counts[idx] : 0;
  }
  part[t] = s;
  __syncthreads();
  for (int off = 1; off < 1024; off <<= 1) {
    int v = (t >= off) ? part[t - off] : 0;
    __syncthreads();
    part[t] += v;
    __syncthreads();
  }
  int pre = (t > 0) ? part[t - 1] : 0;
#pragma unroll
  for (int i = 0; i < 20; i++) {
    int idx = base + i;
    if (idx <= NN) row_ptr[idx] = pre + loc[i];
  }
}

// scatter using counts as down-counting cursor (no separate fill array)
__global__ __launch_bounds__(256)
void k_scatter(const int* __restrict__ ei, const int* __restrict__ row_ptr,
               int* __restrict__ counts, int* __restrict__ csr_src) {
  int e = blockIdx.x * 256 + threadIdx.x;
  if (e >= ETOT) return;
  int s_, d_;
  if (e < NE) { s_ = ei[e]; d_ = ei[NE + e]; } else { s_ = d_ = e - NE; }
  int old = atomicSub(&counts[d_], 1);
  csr_src[row_ptr[d_] + old - 1] = s_;
}

// ---------------- GEMM1: 256x256, role-staggered waves, 1 barrier per K-tile ----------------
// (best measured variant: R6, 293-303 us — FROZEN)

#define NT1 48

#define STAGE_ONE do { \
  if (sctr < 4 * NT1) { \
    int ts_ = sctr >> 2, u_ = sctr & 3, sb_ = ts_ & 1; \
    const unsigned short* gb_; char* lb_; int rb_; \
    if (u_ == 0)      { gb_ = A; rb_ = bmBase + 128; lb_ = lds + (sb_*2+1)*16384; } \
    else if (u_ == 1) { gb_ = B; rb_ = bnBase + 128; lb_ = lds + 65536 + (sb_*2+1)*16384; } \
    else if (u_ == 2) { gb_ = B; rb_ = bnBase;       lb_ = lds + 65536 + (sb_*2+0)*16384; } \
    else              { gb_ = A; rb_ = bmBase;       lb_ = lds + (sb_*2+0)*16384; } \
    const unsigned short* g0_ = gb_ + (size_t)(rb_ + trow) * 3072 + ts_ * 64 + scol; \
    llds16(g0_, lb_ + wid * 1024); \
    llds16(g0_ + (size_t)64 * 3072, lb_ + 8192 + wid * 1024); \
    sctr++; \
  } \
} while (0)

#define RDA(DST, BASE) do { \
  _Pragma("unroll") \
  for (int mi = 0; mi < 2; mi++) { \
    int r_ = rw * 32 + mi * 16 + l15; \
    DST[0][mi] = *(const bf16x8*)((BASE) + r_ * 128 + sw0); \
    DST[1][mi] = *(const bf16x8*)((BASE) + r_ * 128 + sw1); \
  } \
} while (0)

#define RDB(DST, BASE) do { \
  _Pragma("unroll") \
  for (int ni = 0; ni < 4; ni++) { \
    int r_ = cw * 64 + ni * 16 + l15; \
    DST[0][ni] = *(const bf16x8*)((BASE) + r_ * 128 + sw0); \
    DST[1][ni] = *(const bf16x8*)((BASE) + r_ * 128 + sw1); \
  } \
} while (0)

#define MF(MH, NH, AV, BV) do { \
  __builtin_amdgcn_s_setprio(1); \
  _Pragma("unroll") \
  for (int mi = 0; mi < 2; mi++) \
    _Pragma("unroll") \
    for (int ni = 0; ni < 4; ni++) { \
      acc[MH][NH][mi][ni] = __builtin_amdgcn_mfma_f32_16x16x32_bf16(AV[0][mi], BV[0][ni], acc[MH][NH][mi][ni], 0, 0, 0); \
      acc[MH][NH][mi][ni] = __builtin_amdgcn_mfma_f32_16x16x32_bf16(AV[1][mi], BV[1][ni], acc[MH][NH][mi][ni], 0, 0, 0); \
    } \
  __builtin_amdgcn_s_setprio(0); \
} while (0)

__global__ __launch_bounds__(512, 2)
void gemm256(const unsigned short* __restrict__ A, const unsigned short* __restrict__ B,
             unsigned short* __restrict__ C) {
  __shared__ char lds[131072];
  int tid = threadIdx.x, wid = tid >> 6, lane = tid & 63;
  int l15 = lane & 15;
  int rw = wid & 3, cw = wid >> 2;
  int role = (wid >> 2) & 1;
  int bid = blockIdx.x;
  int bn = bid & 7, bm = bid >> 3;
  int bmBase = bm * 256, bnBase = bn * 256;
  int trow = tid >> 3;
  int scol = ((tid & 7) ^ ((tid >> 3) & 7)) * 8;
  int sw0 = (((lane >> 4) + 0) ^ (lane & 7)) * 16;
  int sw1 = (((lane >> 4) + 4) ^ (lane & 7)) * 16;
  f32x4 acc[2][2][2][4] = {};

  int sctr = 0;
  for (int i = 0; i < 4; i++) STAGE_ONE;
  asm volatile("s_waitcnt vmcnt(0)" ::: "memory");
  __builtin_amdgcn_s_barrier();
  asm volatile("" ::: "memory");

  for (int t = 0; t < NT1; t++) {
    int buf = t & 1;
    const char* A0h = lds + (buf * 2 + 0) * 16384;
    const char* A1h = lds + (buf * 2 + 1) * 16384;
    const char* B0h = lds + 65536 + (buf * 2 + 0) * 16384;
    const char* B1h = lds + 65536 + (buf * 2 + 1) * 16384;
    bf16x8 a0[2][2], a1[2][2], b0[2][4], b1[2][4];

    if (role == 0) {
      STAGE_ONE;
      RDA(a0, A0h); RDB(b0, B0h);
      MF(0, 0, a0, b0);
      STAGE_ONE;
      RDA(a1, A1h);
      MF(1, 0, a1, b0);
      STAGE_ONE;
      RDB(b1, B1h);
      MF(1, 1, a1, b1);
      STAGE_ONE;
      MF(0, 1, a0, b1);
    } else {
      STAGE_ONE;
      RDA(a1, A1h); RDB(b1, B1h);
      MF(1, 1, a1, b1);
      STAGE_ONE;
      RDA(a0, A0h);
      MF(0, 1, a0, b1);
      STAGE_ONE;
      RDB(b0, B0h);
      MF(0, 0, a0, b0);
      STAGE_ONE;
      MF(1, 0, a1, b0);
    }
    asm volatile("s_waitcnt vmcnt(0)" ::: "memory");
    __builtin_amdgcn_s_barrier();
    asm volatile("" ::: "memory");
  }

  unsigned short (*sq)[128] = (unsigned short (*)[128])lds;
#pragma unroll
  for (int mh = 0; mh < 2; mh++)
#pragma unroll
    for (int nh = 0; nh < 2; nh++) {
      __syncthreads();
#pragma unroll
      for (int mi = 0; mi < 2; mi++)
#pragma unroll
        for (int ni = 0; ni < 4; ni++)
#pragma unroll
          for (int r = 0; r < 4; r++)
            sq[rw * 32 + mi * 16 + (lane >> 4) * 4 + r][cw * 64 + ni * 16 + l15] =
                f2bf(acc[mh][nh][mi][ni][r]);
      __syncthreads();
#pragma unroll
      for (int it = 0; it < 4; it++) {
        int idx = it * 512 + tid;
        int row = idx >> 4, ch = idx & 15;
        *(u16x8*)(C + (size_t)(bmBase + mh * 128 + row) * NCOL1 + bnBase + nh * 128 + ch * 8) =
            *(const u16x8*)&sq[row][ch * 8];
      }
    }
}

// ---------------- layer-2 GEMM (128-tile m97 structure), both branches, K=512 ----------------

__global__ __launch_bounds__(256)
void gemm_l2(const unsigned short* __restrict__ As, const unsigned short* __restrict__ Bs,
             float* __restrict__ Cs,
             const unsigned short* __restrict__ Ap, const unsigned short* __restrict__ Bp,
             float* __restrict__ Cp) {
  const int K = LDA2, lda = LDA2, ldb = LDA2, ldc = 128, mreal = NN;
  const unsigned short* A = blockIdx.y ? Ap : As;
  const unsigned short* B = blockIdx.y ? Bp : Bs;
  float* C = blockIdx.y ? Cp : Cs;
  __shared__ char smem_raw[16384];
  unsigned short* sA = (unsigned short*)smem_raw;
  unsigned short* sB = sA + 128 * 32;
  int bm = blockIdx.x;
  int tid = threadIdx.x, wid = tid >> 6, lane = tid & 63;
  int wr = wid >> 1, wc = wid & 1;
  f32x4 acc[4][4] = {};

  int ar = 32 * wid + (lane >> 2);
  int acol = (lane & 3) * 8;
  const unsigned short* Ag = A + (size_t)(bm * 128 + ar) * lda + acol;
  const unsigned short* Bg = B + (size_t)ar * ldb + acol;
  unsigned short* la0 = sA + (wid * 2) * 512;
  unsigned short* lb0 = sB + (wid * 2) * 512;
  int frow = lane & 15, koff = (lane >> 4) * 8;

  for (int kt = 0; kt < K; kt += 32) {
    llds16(Ag + kt, la0);
    llds16(Ag + kt + (size_t)16 * lda, la0 + 512);
    llds16(Bg + kt, lb0);
    llds16(Bg + kt + (size_t)16 * ldb, lb0 + 512);
    __syncthreads();
    bf16x8 af[4], bfr[4];
#pragma unroll
    for (int mi = 0; mi < 4; mi++)
      af[mi] = *(const bf16x8*)(sA + (wr * 64 + mi * 16 + frow) * 32 + koff);
#pragma unroll
    for (int ni = 0; ni < 4; ni++)
      bfr[ni] = *(const bf16x8*)(sB + (wc * 64 + ni * 16 + frow) * 32 + koff);
#pragma unroll
    for (int mi = 0; mi < 4; mi++)
#pragma unroll
      for (int ni = 0; ni < 4; ni++)
        acc[mi][ni] = __builtin_amdgcn_mfma_f32_16x16x32_bf16(af[mi], bfr[ni], acc[mi][ni], 0, 0, 0);
    __syncthreads();
  }

#pragma unroll
  for (int mi = 0; mi < 4; mi++) {
    int grow0 = bm * 128 + wr * 64 + mi * 16 + (lane >> 4) * 4;
#pragma unroll
    for (int ni = 0; ni < 4; ni++) {
      int gcol = wc * 64 + ni * 16 + (lane & 15);
#pragma unroll
      for (int r = 0; r < 4; r++) {
        int grow = grow0 + r;
        if (grow < mreal) C[(size_t)grow * ldc + gcol] = acc[mi][ni][r];
      }
    }
  }
}

// ---------------- layer-1 edge agg: both branches per wave, depth-3 slot pipeline ----------

__global__ __launch_bounds__(256, 4)
void edge_agg1(const unsigned short* __restrict__ XL1,
               const int* __restrict__ row_ptr, const int* __restrict__ csr_src,
               const float* __restrict__ att_s, const float* __restrict__ att_p,
               const float* __restrict__ b_s, const float* __restrict__ b_p,
               unsigned short* __restrict__ A2s, unsigned short* __restrict__ A2p) {
  int n = (blockIdx.x * 256 + threadIdx.x) >> 6;
  if (n >= NN) return;
  int lane = threadIdx.x & 63;
  int cb = lane * 8;
  float xs[8], xp[8], as_[8], ap_[8], aggs[8], aggp[8];
  {
    bf16x8 xsv = *(const bf16x8*)(XL1 + (size_t)n * NCOL1 + 512 + cb);
    bf16x8 xpv = *(const bf16x8*)(XL1 + (size_t)n * NCOL1 + 1536 + cb);
    float4 a0 = *(const float4*)(att_s + cb), a1 = *(const float4*)(att_s + cb + 4);
    float4 a2 = *(const float4*)(att_p + cb), a3 = *(const float4*)(att_p + cb + 4);
    as_[0]=a0.x; as_[1]=a0.y; as_[2]=a0.z; as_[3]=a0.w; as_[4]=a1.x; as_[5]=a1.y; as_[6]=a1.z; as_[7]=a1.w;
    ap_[0]=a2.x; ap_[1]=a2.y; ap_[2]=a2.z; ap_[3]=a2.w; ap_[4]=a3.x; ap_[5]=a3.y; ap_[6]=a3.z; ap_[7]=a3.w;
#pragma unroll
    for (int j = 0; j < 8; j++) { xs[j] = (float)xsv[j]; xp[j] = (float)xpv[j]; aggs[j] = 0.f; aggp[j] = 0.f; }
  }
  float Ms = -1e30f, Ss = 0.f, Mp = -1e30f, Sp = 0.f;
  int p0 = row_ptr[n], pe = row_ptr[n + 1];
  int deg = pe - p0;

  auto gS = [&](int s) { return *(const bf16x8*)(XL1 + (size_t)s * NCOL1 + cb); };
  auto gP = [&](int s) { return *(const bf16x8*)(XL1 + (size_t)s * NCOL1 + 1024 + cb); };
  auto compute = [&](bf16x8 cs, bf16x8 cp) {
    float mjs[8], mjp[8], ps_ = 0.f, pp_ = 0.f;
#pragma unroll
    for (int j = 0; j < 8; j++) {
      mjs[j] = (float)cs[j];
      float t = mjs[j] + xs[j];
      t = (t > 0.f) ? t : 0.2f * t;
      ps_ = fmaf(as_[j], t, ps_);
      mjp[j] = (float)cp[j];
      float u = mjp[j] + xp[j];
      u = (u > 0.f) ? u : 0.2f * u;
      pp_ = fmaf(ap_[j], u, pp_);
    }
#pragma unroll
    for (int w = 1; w < 16; w <<= 1) { ps_ += __shfl_xor(ps_, w); pp_ += __shfl_xor(pp_, w); }
    float nms = fmaxf(Ms, ps_);
    float fs = __expf(Ms - nms), ws_ = __expf(ps_ - nms);
    Ss = Ss * fs + ws_;
    float nmp = fmaxf(Mp, pp_);
    float fp = __expf(Mp - nmp), wp_ = __expf(pp_ - nmp);
    Sp = Sp * fp + wp_;
#pragma unroll
    for (int j = 0; j < 8; j++) {
      aggs[j] = aggs[j] * fs + ws_ * mjs[j];
      aggp[j] = aggp[j] * fp + wp_ * mjp[j];
    }
    Ms = nms; Mp = nmp;
  };

  bf16x8 s0s, s0p, s1s, s1p, s2s, s2p;
  {
    int i0 = csr_src[p0];
    s0s = gS(i0); s0p = gP(i0);
    if (deg > 1) { int i1 = csr_src[p0 + 1]; s1s = gS(i1); s1p = gP(i1); }
    if (deg > 2) { int i2 = csr_src[p0 + 2]; s2s = gS(i2); s2p = gP(i2); }
  }
  int p = p0;
  for (; p + 2 < pe; p += 3) {
    int q = p + 3;
    bf16x8 c0 = s0s, d0 = s0p;
    if (q < pe)     { int i = csr_src[q];     s0s = gS(i); s0p = gP(i); }
    compute(c0, d0);
    bf16x8 c1 = s1s, d1 = s1p;
    if (q + 1 < pe) { int i = csr_src[q + 1]; s1s = gS(i); s1p = gP(i); }
    compute(c1, d1);
    bf16x8 c2 = s2s, d2 = s2p;
    if (q + 2 < pe) { int i = csr_src[q + 2]; s2s = gS(i); s2p = gP(i); }
    compute(c2, d2);
  }
  int r = pe - p;
  if (r > 0) compute(s0s, s0p);
  if (r > 1) compute(s1s, s1p);

  float invs = 1.f / Ss, invp = 1.f / Sp;
  u16x8 hs, hp;
#pragma unroll
  for (int j = 0; j < 8; j++) {
    float v = fmaxf(aggs[j] * invs + b_s[cb + j], 0.f);
    hs[j] = f2bf(v);
    float u = aggp[j] * invp + b_p[cb + j];
    hp[j] = f2bf(u);
  }
  *(u16x8*)(A2s + (size_t)n * LDA2 + cb) = hs;
  *(u16x8*)(A2p + (size_t)n * LDA2 + cb) = hp;
}

// ---------------- layer-2 edge agg + epilogue: both branches per wave, depth-4 pipeline ----

__global__ __launch_bounds__(256)
void edge_agg2(const float* __restrict__ C2s, const float* __restrict__ C2p,
               const int* __restrict__ row_ptr, const int* __restrict__ csr_src,
               const float* __restrict__ att_s, const float* __restrict__ att_p,
               const float* __restrict__ b_s, const float* __restrict__ b_p,
               float* __restrict__ out) {
  int n = (blockIdx.x * 256 + threadIdx.x) >> 6;
  if (n >= NN) return;
  int lane = threadIdx.x & 63;
  float xrs = C2s[(size_t)n * 128 + 64 + lane];
  float xrp = C2p[(size_t)n * 128 + 64 + lane];
  float ats = att_s[lane], atp = att_p[lane];
  float Ms = -1e30f, Ss = 0.f, ags = 0.f;
  float Mp = -1e30f, Sp = 0.f, agp = 0.f;
  int p0 = row_ptr[n], pe = row_ptr[n + 1];
  int deg = pe - p0;

  auto compute = [&](float cs, float cp) {
    float t = cs + xrs; t = (t > 0.f) ? t : 0.2f * t;
    float u = cp + xrp; u = (u > 0.f) ? u : 0.2f * u;
    float ps_ = ats * t, pp_ = atp * u;
#pragma unroll
    for (int w = 1; w < 64; w <<= 1) { ps_ += __shfl_xor(ps_, w); pp_ += __shfl_xor(pp_, w); }
    float nms = fmaxf(Ms, ps_);
    float fs = __expf(Ms - nms), ws_ = __expf(ps_ - nms);
    Ss = Ss * fs + ws_; ags = ags * fs + ws_ * cs; Ms = nms;
    float nmp = fmaxf(Mp, pp_);
    float fp = __expf(Mp - nmp), wp_ = __expf(pp_ - nmp);
    Sp = Sp * fp + wp_; agp = agp * fp + wp_ * cp; Mp = nmp;
  };

  float s0c, s0d, s1c, s1d, s2c, s2d, s3c, s3d;
  {
    int i0 = csr_src[p0];
    s0c = C2s[(size_t)i0 * 128 + lane]; s0d = C2p[(size_t)i0 * 128 + lane];
    if (deg > 1) { int i1 = csr_src[p0 + 1]; s1c = C2s[(size_t)i1 * 128 + lane]; s1d = C2p[(size_t)i1 * 128 + lane]; }
    if (deg > 2) { int i2 = csr_src[p0 + 2]; s2c = C2s[(size_t)i2 * 128 + lane]; s2d = C2p[(size_t)i2 * 128 + lane]; }
    if (deg > 3) { int i3 = csr_src[p0 + 3]; s3c = C2s[(size_t)i3 * 128 + lane]; s3d = C2p[(size_t)i3 * 128 + lane]; }
  }
  int p = p0;
  for (; p + 3 < pe; p += 4) {
    int q = p + 4;
    float c0 = s0c, d0 = s0d;
    if (q < pe)     { int i = csr_src[q];     s0c = C2s[(size_t)i * 128 + lane]; s0d = C2p[(size_t)i * 128 + lane]; }
    compute(c0, d0);
    float c1 = s1c, d1 = s1d;
    if (q + 1 < pe) { int i = csr_src[q + 1]; s1c = C2s[(size_t)i * 128 + lane]; s1d = C2p[(size_t)i * 128 + lane]; }
    compute(c1, d1);
    float c2 = s2c, d2 = s2d;
    if (q + 2 < pe) { int i = csr_src[q + 2]; s2c = C2s[(size_t)i * 128 + lane]; s2d = C2p[(size_t)i * 128 + lane]; }
    compute(c2, d2);
    float c3 = s3c, d3 = s3d;
    if (q + 3 < pe) { int i = csr_src[q + 3]; s3c = C2s[(size_t)i * 128 + lane]; s3d = C2p[(size_t)i * 128 + lane]; }
    compute(c3, d3);
  }
  int r = pe - p;
  if (r > 0) compute(s0c, s0d);
  if (r > 1) compute(s1c, s1d);
  if (r > 2) compute(s2c, s2d);

  float vs = ags / Ss + b_s[lane];
  float vp = agp / Sp + b_p[lane];
  if (lane < 32) {
    out[(size_t)n * 64 + lane] = vs;
    out[(size_t)n * 64 + 32 + lane] = vp;
  } else {
    float sps = fmaxf(vs, 0.f) + log1pf(__expf(-fabsf(vs))) + 1e-6f;
    float spp = fmaxf(vp, 0.f) + log1pf(__expf(-fabsf(vp))) + 1e-6f;
    out[(size_t)MU_SZ + n * 64 + (lane - 32)] = sps;
    out[(size_t)MU_SZ + n * 64 + 32 + (lane - 32)] = spp;
  }
}

// ---------------- host ----------------

extern "C" void kernel_launch(void* const* d_in, const int* in_sizes, int n_in,
                              void* d_out, int out_size, void* d_ws, size_t ws_size,
                              hipStream_t stream) {
  const float* x      = (const float*)d_in[0];
  const int*   ei     = (const int*)d_in[1];
  const float* Wl_s1  = (const float*)d_in[2];
  const float* Wr_s1  = (const float*)d_in[3];
  const float* att_s1 = (const float*)d_in[4];
  const float* b_s1   = (const float*)d_in[5];
  const float* Wl_s2  = (const float*)d_in[6];
  const float* Wr_s2  = (const float*)d_in[7];
  const float* att_s2 = (const float*)d_in[8];
  const float* b_s2   = (const float*)d_in[9];
  const float* Wl_p1  = (const float*)d_in[10];
  const float* Wr_p1  = (const float*)d_in[11];
  const float* att_p1 = (const float*)d_in[12];
  const float* b_p1   = (const float*)d_in[13];
  const float* Wl_p2  = (const float*)d_in[14];
  const float* Wr_p2  = (const float*)d_in[15];
  const float* att_p2 = (const float*)d_in[16];
  const float* b_p2   = (const float*)d_in[17];

  char* ws = (char*)d_ws;
  unsigned short* Xb   = (unsigned short*)(ws + 0);           // 20224*3072*2 = 124,256,256
  unsigned short* A2s  = (unsigned short*)(ws + 0);           // 20096*512*2 = 20,578,304 (after Xb dead)
  unsigned short* A2p  = (unsigned short*)(ws + 20578304);    // 20,578,304
  float*          C2s  = (float*)(ws + 41156608);             // 10,240,000
  float*          C2p  = (float*)(ws + 51396608);             // 10,240,000
  unsigned short* B2s  = (unsigned short*)(ws + 61636608);    // 131,072 (aliases Xb; written post-gemm256)
  unsigned short* B2p  = (unsigned short*)(ws + 61767680);    // 131,072
  unsigned short* Wp   = (unsigned short*)(ws + 124256256);   // 12,582,912
  unsigned short* XL1  = (unsigned short*)(ws + 136839168);   // 20224*2048*2 = 82,837,504
  int* counts  = (int*)(ws + 219676672);                      // 80,000
  int* row_ptr = (int*)(ws + 219836672);                      // 80,004
  int* csr_src = (int*)(ws + 219916688);                      // 1,360,000

  hipMemsetAsync(counts, 0, NN * sizeof(int), stream);

  k_prep<<<PB_CVT, 256, 0, stream>>>(x, Xb, Wl_s1, Wr_s1, Wl_p1, Wr_p1, Wp, ei, counts);
  k_scan<<<1, 1024, 0, stream>>>(counts, row_ptr);
  k_scatter<<<(ETOT + 255) / 256, 256, 0, stream>>>(ei, row_ptr, counts, csr_src);

  // XL1[n, 0:512|512:1024|1024:1536|1536:2048] = x@{Wl_s1|Wr_s1|Wl_p1|Wr_p1}, bf16
  gemm256<<<632, 512, 0, stream>>>(Xb, Wp, XL1);

  k_pack_w2b<<<512, 256, 0, stream>>>(Wl_s2, Wr_s2, Wl_p2, Wr_p2, B2s, B2p);

  edge_agg1<<<5000, 256, 0, stream>>>(XL1, row_ptr, csr_src, att_s1, att_p1, b_s1, b_p1, A2s, A2p);

  gemm_l2<<<dim3(157, 2), 256, 0, stream>>>(A2s, B2s, C2s, A2p, B2p, C2p);

  edge_agg2<<<5000, 256, 0, stream>>>(C2s, C2p, row_ptr, csr_src, att_s2, att_p2, b_s2, b_p2, (float*)d_out);
}

// Round 16
// 575.114 us; speedup vs baseline: 1.0920x; 1.0920x over previous
//
#include <hip/hip_runtime.h>
#include <cstdint>

// Problem constants
#define NN     20000      // nodes
#define NE     320000     // input edges
#define ETOT   340000     // edges + self loops
#define K1R    3000       // in_dim
#define K1     3072       // padded K for GEMM1
#define NPAD   20224      // 79*256 padded rows (256-tile GEMM1)
#define NCOL1  2048       // 4 x 512 packed outputs (xl_s|xr_s|xl_p|xr_p)
#define LDA2   512        // layer-2 A row (plain bf16)
#define MU_SZ  1280000    // 20000*64

typedef __bf16 bf16x8 __attribute__((ext_vector_type(8)));
typedef float f32x4 __attribute__((ext_vector_type(4)));
typedef unsigned short u16x8 __attribute__((ext_vector_type(8)));

__device__ inline unsigned short f2bf(float f) {
  union { float f; unsigned u; } v; v.f = f;
  unsigned r = v.u + 0x7FFFu + ((v.u >> 16) & 1u);
  return (unsigned short)(r >> 16);
}
__device__ inline float bf2f(unsigned short h) {
  union { unsigned u; float f; } v; v.u = ((unsigned)h) << 16;
  return v.f;
}

typedef const __attribute__((address_space(1))) void* gas1_t;
typedef __attribute__((address_space(3))) void* las3_t;
__device__ inline void llds16(const void* g, void* l) {
  __builtin_amdgcn_global_load_lds((gas1_t)(uintptr_t)g,
                                   (las3_t)(uint32_t)(uintptr_t)l, 16, 0, 0);
}

// ---------------- mega-prep: pack_w1 | count | convert_x in one launch ----------
// NOTE: pack_w2b is NOT fused here — B2s/B2p alias Xb's region and may only be
// written AFTER gemm256 has consumed Xb (R12's fusion corrupted Xb -> absmax 66).
#define PB_PW1  1536                       // pack_w1: 48 x 32 blocks
#define PB_CNT  (PB_PW1 + 1329)            // count: ceil(ETOT/256)
#define PB_CVT  (PB_CNT + 30336)           // convert: NPAD*384/256

__global__ __launch_bounds__(256)
void k_prep(const float* __restrict__ X, unsigned short* __restrict__ Xb,
            const float* __restrict__ W0, const float* __restrict__ W1,
            const float* __restrict__ W2, const float* __restrict__ W3,
            unsigned short* __restrict__ Wp,
            const int* __restrict__ ei, int* __restrict__ counts) {
  __shared__ float tile[64][65];
  int b = blockIdx.x, tid = threadIdx.x;

  if (b < PB_PW1) {
    int k0 = (b % 48) * 64, n0 = (b / 48) * 64;
    int m = n0 >> 9, c0 = n0 & 511;
    const float* W = (m == 0) ? W0 : (m == 1) ? W1 : (m == 2) ? W2 : W3;
    int tx = tid & 63, ty = tid >> 6;
#pragma unroll
    for (int rep = 0; rep < 16; rep++) {
      int i = ty + rep * 4;
      int k = k0 + i;
      tile[i][tx] = (k < K1R) ? W[(size_t)k * 512 + c0 + tx] : 0.f;
    }
    __syncthreads();
#pragma unroll
    for (int rep = 0; rep < 16; rep++) {
      int i = ty + rep * 4;
      Wp[(size_t)(n0 + i) * K1 + k0 + tx] = f2bf(tile[tx][i]);
    }
  } else if (b < PB_CNT) {
    int e = (b - PB_PW1) * 256 + tid;
    if (e < ETOT) {
      int dst = (e < NE) ? ei[NE + e] : (e - NE);
      atomicAdd(&counts[dst], 1);
    }
  } else {
    const int CH = K1 / 8;
    int idx = (b - PB_CNT) * 256 + tid;
    if (idx >= NPAD * CH) return;
    int r = idx / CH, c8 = (idx % CH) * 8;
    u16x8 o;
    if (r < NN && c8 < K1R) {
      const float4* p = (const float4*)(X + (size_t)r * K1R + c8);
      float4 a = p[0], bb = p[1];
      o[0]=f2bf(a.x); o[1]=f2bf(a.y); o[2]=f2bf(a.z); o[3]=f2bf(a.w);
      o[4]=f2bf(bb.x); o[5]=f2bf(bb.y); o[6]=f2bf(bb.z); o[7]=f2bf(bb.w);
    } else {
#pragma unroll
      for (int j = 0; j < 8; j++) o[j] = 0;
    }
    *(u16x8*)(Xb + (size_t)r * K1 + c8) = o;
  }
}

// ---------------- pack layer-2 weights (launched AFTER gemm256; B2 aliases Xb) ----------

__global__ __launch_bounds__(256)
void k_pack_w2b(const float* __restrict__ Wl_s, const float* __restrict__ Wr_s,
                const float* __restrict__ Wl_p, const float* __restrict__ Wr_p,
                unsigned short* __restrict__ B2s, unsigned short* __restrict__ B2p) {
  int gidx = blockIdx.x * 256 + threadIdx.x;   // grid 512 -> 131072
  int br = gidx >> 16, idx = gidx & 65535;
  const float* Wl = br ? Wl_p : Wl_s;
  const float* Wr = br ? Wr_p : Wr_s;
  unsigned short* B2 = br ? B2p : B2s;
  int n = idx >> 9, k = idx & 511;
  float v = (n < 64) ? Wl[(size_t)k * 64 + n] : Wr[(size_t)k * 64 + (n - 64)];
  B2[idx] = f2bf(v);
}

// ---------------- CSR scan + scatter ----------------

__global__ void k_scan(const int* __restrict__ counts, int* __restrict__ row_ptr) {
  __shared__ int part[1024];
  int t = threadIdx.x;
  int base = t * 20;
  int loc[20];
  int s = 0;
#pragma unroll
  for (int i = 0; i < 20; i++) {
    int idx = base + i;
    loc[i] = s;
    s += (idx < NN) ? counts[idx] : 0;
  }
  part[t] = s;
  __syncthreads();
  for (int off = 1; off < 1024; off <<= 1) {
    int v = (t >= off) ? part[t - off] : 0;
    __syncthreads();
    part[t] += v;
    __syncthreads();
  }
  int pre = (t > 0) ? part[t - 1] : 0;
#pragma unroll
  for (int i = 0; i < 20; i++) {
    int idx = base + i;
    if (idx <= NN) row_ptr[idx] = pre + loc[i];
  }
}

// scatter using counts as down-counting cursor (no separate fill array)
__global__ __launch_bounds__(256)
void k_scatter(const int* __restrict__ ei, const int* __restrict__ row_ptr,
               int* __restrict__ counts, int* __restrict__ csr_src) {
  int e = blockIdx.x * 256 + threadIdx.x;
  if (e >= ETOT) return;
  int s_, d_;
  if (e < NE) { s_ = ei[e]; d_ = ei[NE + e]; } else { s_ = d_ = e - NE; }
  int old = atomicSub(&counts[d_], 1);
  csr_src[row_ptr[d_] + old - 1] = s_;
}

// ---------------- GEMM1: 256x256, role-staggered waves, 1 barrier per K-tile ----------------
// (best measured variant: R6, 293-303 us — FROZEN)

#define NT1 48

#define STAGE_ONE do { \
  if (sctr < 4 * NT1) { \
    int ts_ = sctr >> 2, u_ = sctr & 3, sb_ = ts_ & 1; \
    const unsigned short* gb_; char* lb_; int rb_; \
    if (u_ == 0)      { gb_ = A; rb_ = bmBase + 128; lb_ = lds + (sb_*2+1)*16384; } \
    else if (u_ == 1) { gb_ = B; rb_ = bnBase + 128; lb_ = lds + 65536 + (sb_*2+1)*16384; } \
    else if (u_ == 2) { gb_ = B; rb_ = bnBase;       lb_ = lds + 65536 + (sb_*2+0)*16384; } \
    else              { gb_ = A; rb_ = bmBase;       lb_ = lds + (sb_*2+0)*16384; } \
    const unsigned short* g0_ = gb_ + (size_t)(rb_ + trow) * 3072 + ts_ * 64 + scol; \
    llds16(g0_, lb_ + wid * 1024); \
    llds16(g0_ + (size_t)64 * 3072, lb_ + 8192 + wid * 1024); \
    sctr++; \
  } \
} while (0)

#define RDA(DST, BASE) do { \
  _Pragma("unroll") \
  for (int mi = 0; mi < 2; mi++) { \
    int r_ = rw * 32 + mi * 16 + l15; \
    DST[0][mi] = *(const bf16x8*)((BASE) + r_ * 128 + sw0); \
    DST[1][mi] = *(const bf16x8*)((BASE) + r_ * 128 + sw1); \
  } \
} while (0)

#define RDB(DST, BASE) do { \
  _Pragma("unroll") \
  for (int ni = 0; ni < 4; ni++) { \
    int r_ = cw * 64 + ni * 16 + l15; \
    DST[0][ni] = *(const bf16x8*)((BASE) + r_ * 128 + sw0); \
    DST[1][ni] = *(const bf16x8*)((BASE) + r_ * 128 + sw1); \
  } \
} while (0)

#define MF(MH, NH, AV, BV) do { \
  __builtin_amdgcn_s_setprio(1); \
  _Pragma("unroll") \
  for (int mi = 0; mi < 2; mi++) \
    _Pragma("unroll") \
    for (int ni = 0; ni < 4; ni++) { \
      acc[MH][NH][mi][ni] = __builtin_amdgcn_mfma_f32_16x16x32_bf16(AV[0][mi], BV[0][ni], acc[MH][NH][mi][ni], 0, 0, 0); \
      acc[MH][NH][mi][ni] = __builtin_amdgcn_mfma_f32_16x16x32_bf16(AV[1][mi], BV[1][ni], acc[MH][NH][mi][ni], 0, 0, 0); \
    } \
  __builtin_amdgcn_s_setprio(0); \
} while (0)

__global__ __launch_bounds__(512, 2)
void gemm256(const unsigned short* __restrict__ A, const unsigned short* __restrict__ B,
             unsigned short* __restrict__ C) {
  __shared__ char lds[131072];
  int tid = threadIdx.x, wid = tid >> 6, lane = tid & 63;
  int l15 = lane & 15;
  int rw = wid & 3, cw = wid >> 2;
  int role = (wid >> 2) & 1;
  int bid = blockIdx.x;
  int bn = bid & 7, bm = bid >> 3;
  int bmBase = bm * 256, bnBase = bn * 256;
  int trow = tid >> 3;
  int scol = ((tid & 7) ^ ((tid >> 3) & 7)) * 8;
  int sw0 = (((lane >> 4) + 0) ^ (lane & 7)) * 16;
  int sw1 = (((lane >> 4) + 4) ^ (lane & 7)) * 16;
  f32x4 acc[2][2][2][4] = {};

  int sctr = 0;
  for (int i = 0; i < 4; i++) STAGE_ONE;
  asm volatile("s_waitcnt vmcnt(0)" ::: "memory");
  __builtin_amdgcn_s_barrier();
  asm volatile("" ::: "memory");

  for (int t = 0; t < NT1; t++) {
    int buf = t & 1;
    const char* A0h = lds + (buf * 2 + 0) * 16384;
    const char* A1h = lds + (buf * 2 + 1) * 16384;
    const char* B0h = lds + 65536 + (buf * 2 + 0) * 16384;
    const char* B1h = lds + 65536 + (buf * 2 + 1) * 16384;
    bf16x8 a0[2][2], a1[2][2], b0[2][4], b1[2][4];

    if (role == 0) {
      STAGE_ONE;
      RDA(a0, A0h); RDB(b0, B0h);
      MF(0, 0, a0, b0);
      STAGE_ONE;
      RDA(a1, A1h);
      MF(1, 0, a1, b0);
      STAGE_ONE;
      RDB(b1, B1h);
      MF(1, 1, a1, b1);
      STAGE_ONE;
      MF(0, 1, a0, b1);
    } else {
      STAGE_ONE;
      RDA(a1, A1h); RDB(b1, B1h);
      MF(1, 1, a1, b1);
      STAGE_ONE;
      RDA(a0, A0h);
      MF(0, 1, a0, b1);
      STAGE_ONE;
      RDB(b0, B0h);
      MF(0, 0, a0, b0);
      STAGE_ONE;
      MF(1, 0, a1, b0);
    }
    asm volatile("s_waitcnt vmcnt(0)" ::: "memory");
    __builtin_amdgcn_s_barrier();
    asm volatile("" ::: "memory");
  }

  unsigned short (*sq)[128] = (unsigned short (*)[128])lds;
#pragma unroll
  for (int mh = 0; mh < 2; mh++)
#pragma unroll
    for (int nh = 0; nh < 2; nh++) {
      __syncthreads();
#pragma unroll
      for (int mi = 0; mi < 2; mi++)
#pragma unroll
        for (int ni = 0; ni < 4; ni++)
#pragma unroll
          for (int r = 0; r < 4; r++)
            sq[rw * 32 + mi * 16 + (lane >> 4) * 4 + r][cw * 64 + ni * 16 + l15] =
                f2bf(acc[mh][nh][mi][ni][r]);
      __syncthreads();
#pragma unroll
      for (int it = 0; it < 4; it++) {
        int idx = it * 512 + tid;
        int row = idx >> 4, ch = idx & 15;
        *(u16x8*)(C + (size_t)(bmBase + mh * 128 + row) * NCOL1 + bnBase + nh * 128 + ch * 8) =
            *(const u16x8*)&sq[row][ch * 8];
      }
    }
}

// ---------------- layer-2 GEMM (128-tile m97 structure), both branches, K=512 ----------------

__global__ __launch_bounds__(256)
void gemm_l2(const unsigned short* __restrict__ As, const unsigned short* __restrict__ Bs,
             float* __restrict__ Cs,
             const unsigned short* __restrict__ Ap, const unsigned short* __restrict__ Bp,
             float* __restrict__ Cp) {
  const int K = LDA2, lda = LDA2, ldb = LDA2, ldc = 128, mreal = NN;
  const unsigned short* A = blockIdx.y ? Ap : As;
  const unsigned short* B = blockIdx.y ? Bp : Bs;
  float* C = blockIdx.y ? Cp : Cs;
  __shared__ char smem_raw[16384];
  unsigned short* sA = (unsigned short*)smem_raw;
  unsigned short* sB = sA + 128 * 32;
  int bm = blockIdx.x;
  int tid = threadIdx.x, wid = tid >> 6, lane = tid & 63;
  int wr = wid >> 1, wc = wid & 1;
  f32x4 acc[4][4] = {};

  int ar = 32 * wid + (lane >> 2);
  int acol = (lane & 3) * 8;
  const unsigned short* Ag = A + (size_t)(bm * 128 + ar) * lda + acol;
  const unsigned short* Bg = B + (size_t)ar * ldb + acol;
  unsigned short* la0 = sA + (wid * 2) * 512;
  unsigned short* lb0 = sB + (wid * 2) * 512;
  int frow = lane & 15, koff = (lane >> 4) * 8;

  for (int kt = 0; kt < K; kt += 32) {
    llds16(Ag + kt, la0);
    llds16(Ag + kt + (size_t)16 * lda, la0 + 512);
    llds16(Bg + kt, lb0);
    llds16(Bg + kt + (size_t)16 * ldb, lb0 + 512);
    __syncthreads();
    bf16x8 af[4], bfr[4];
#pragma unroll
    for (int mi = 0; mi < 4; mi++)
      af[mi] = *(const bf16x8*)(sA + (wr * 64 + mi * 16 + frow) * 32 + koff);
#pragma unroll
    for (int ni = 0; ni < 4; ni++)
      bfr[ni] = *(const bf16x8*)(sB + (wc * 64 + ni * 16 + frow) * 32 + koff);
#pragma unroll
    for (int mi = 0; mi < 4; mi++)
#pragma unroll
      for (int ni = 0; ni < 4; ni++)
        acc[mi][ni] = __builtin_amdgcn_mfma_f32_16x16x32_bf16(af[mi], bfr[ni], acc[mi][ni], 0, 0, 0);
    __syncthreads();
  }

#pragma unroll
  for (int mi = 0; mi < 4; mi++) {
    int grow0 = bm * 128 + wr * 64 + mi * 16 + (lane >> 4) * 4;
#pragma unroll
    for (int ni = 0; ni < 4; ni++) {
      int gcol = wc * 64 + ni * 16 + (lane & 15);
#pragma unroll
      for (int r = 0; r < 4; r++) {
        int grow = grow0 + r;
        if (grow < mreal) C[(size_t)grow * ldc + gcol] = acc[mi][ni][r];
      }
    }
  }
}

// ---------------- layer-1 edge agg: both branches per wave, depth-2 unconditional pipeline ----

__global__ __launch_bounds__(256)
void edge_agg1(const unsigned short* __restrict__ XL1,
               const int* __restrict__ row_ptr, const int* __restrict__ csr_src,
               const float* __restrict__ att_s, const float* __restrict__ att_p,
               const float* __restrict__ b_s, const float* __restrict__ b_p,
               unsigned short* __restrict__ A2s, unsigned short* __restrict__ A2p) {
  int n = (blockIdx.x * 256 + threadIdx.x) >> 6;
  if (n >= NN) return;
  int lane = threadIdx.x & 63;
  int cb = lane * 8;
  float xs[8], xp[8], as_[8], ap_[8], aggs[8], aggp[8];
  {
    bf16x8 xsv = *(const bf16x8*)(XL1 + (size_t)n * NCOL1 + 512 + cb);
    bf16x8 xpv = *(const bf16x8*)(XL1 + (size_t)n * NCOL1 + 1536 + cb);
    float4 a0 = *(const float4*)(att_s + cb), a1 = *(const float4*)(att_s + cb + 4);
    float4 a2 = *(const float4*)(att_p + cb), a3 = *(const float4*)(att_p + cb + 4);
    as_[0]=a0.x; as_[1]=a0.y; as_[2]=a0.z; as_[3]=a0.w; as_[4]=a1.x; as_[5]=a1.y; as_[6]=a1.z; as_[7]=a1.w;
    ap_[0]=a2.x; ap_[1]=a2.y; ap_[2]=a2.z; ap_[3]=a2.w; ap_[4]=a3.x; ap_[5]=a3.y; ap_[6]=a3.z; ap_[7]=a3.w;
#pragma unroll
    for (int j = 0; j < 8; j++) { xs[j] = (float)xsv[j]; xp[j] = (float)xpv[j]; aggs[j] = 0.f; aggp[j] = 0.f; }
  }
  float Ms = -1e30f, Ss = 0.f, Mp = -1e30f, Sp = 0.f;
  int p0 = row_ptr[n], pe = row_ptr[n + 1];
  int deg = pe - p0;

  auto gS = [&](int s) { return *(const bf16x8*)(XL1 + (size_t)s * NCOL1 + cb); };
  auto gP = [&](int s) { return *(const bf16x8*)(XL1 + (size_t)s * NCOL1 + 1024 + cb); };
  auto compute = [&](bf16x8 cs, bf16x8 cp) {
    float mjs[8], mjp[8], ps_ = 0.f, pp_ = 0.f;
#pragma unroll
    for (int j = 0; j < 8; j++) {
      mjs[j] = (float)cs[j];
      float t = mjs[j] + xs[j];
      t = (t > 0.f) ? t : 0.2f * t;
      ps_ = fmaf(as_[j], t, ps_);
      mjp[j] = (float)cp[j];
      float u = mjp[j] + xp[j];
      u = (u > 0.f) ? u : 0.2f * u;
      pp_ = fmaf(ap_[j], u, pp_);
    }
#pragma unroll
    for (int w = 1; w < 16; w <<= 1) { ps_ += __shfl_xor(ps_, w); pp_ += __shfl_xor(pp_, w); }
    float nms = fmaxf(Ms, ps_);
    float fs = __expf(Ms - nms), ws_ = __expf(ps_ - nms);
    Ss = Ss * fs + ws_;
    float nmp = fmaxf(Mp, pp_);
    float fp = __expf(Mp - nmp), wp_ = __expf(pp_ - nmp);
    Sp = Sp * fp + wp_;
#pragma unroll
    for (int j = 0; j < 8; j++) {
      aggs[j] = aggs[j] * fs + ws_ * mjs[j];
      aggp[j] = aggp[j] * fp + wp_ * mjp[j];
    }
    Ms = nms; Mp = nmp;
  };

  // depth-2 slots; main loop refills 2 unconditionally (pe-p >= 4 guaranteed)
  bf16x8 s0s, s0p, s1s, s1p;
  {
    int i0 = csr_src[p0];
    s0s = gS(i0); s0p = gP(i0);
    if (deg > 1) { int i1 = csr_src[p0 + 1]; s1s = gS(i1); s1p = gP(i1); }
  }
  int p = p0;
  for (; p + 3 < pe; p += 2) {
    int ia = csr_src[p + 2], ib = csr_src[p + 3];
    bf16x8 n0s = gS(ia), n0p = gP(ia);
    bf16x8 n1s = gS(ib), n1p = gP(ib);
    compute(s0s, s0p);
    compute(s1s, s1p);
    s0s = n0s; s0p = n0p; s1s = n1s; s1p = n1p;
  }
  int r = pe - p;                                // r in {1,2,3}
  if (r == 3) {
    int i = csr_src[p + 2];
    bf16x8 ts = gS(i), tp = gP(i);
    compute(s0s, s0p); compute(s1s, s1p); compute(ts, tp);
  } else if (r == 2) {
    compute(s0s, s0p); compute(s1s, s1p);
  } else {
    compute(s0s, s0p);
  }

  float invs = 1.f / Ss, invp = 1.f / Sp;
  u16x8 hs, hp;
#pragma unroll
  for (int j = 0; j < 8; j++) {
    float v = fmaxf(aggs[j] * invs + b_s[cb + j], 0.f);
    hs[j] = f2bf(v);
    float u = aggp[j] * invp + b_p[cb + j];
    hp[j] = f2bf(u);
  }
  *(u16x8*)(A2s + (size_t)n * LDA2 + cb) = hs;
  *(u16x8*)(A2p + (size_t)n * LDA2 + cb) = hp;
}

// ---------------- layer-2 edge agg + epilogue: both branches per wave, depth-2 pipeline ----

__global__ __launch_bounds__(256)
void edge_agg2(const float* __restrict__ C2s, const float* __restrict__ C2p,
               const int* __restrict__ row_ptr, const int* __restrict__ csr_src,
               const float* __restrict__ att_s, const float* __restrict__ att_p,
               const float* __restrict__ b_s, const float* __restrict__ b_p,
               float* __restrict__ out) {
  int n = (blockIdx.x * 256 + threadIdx.x) >> 6;
  if (n >= NN) return;
  int lane = threadIdx.x & 63;
  float xrs = C2s[(size_t)n * 128 + 64 + lane];
  float xrp = C2p[(size_t)n * 128 + 64 + lane];
  float ats = att_s[lane], atp = att_p[lane];
  float Ms = -1e30f, Ss = 0.f, ags = 0.f;
  float Mp = -1e30f, Sp = 0.f, agp = 0.f;
  int p0 = row_ptr[n], pe = row_ptr[n + 1];
  int deg = pe - p0;

  auto compute = [&](float cs, float cp) {
    float t = cs + xrs; t = (t > 0.f) ? t : 0.2f * t;
    float u = cp + xrp; u = (u > 0.f) ? u : 0.2f * u;
    float ps_ = ats * t, pp_ = atp * u;
#pragma unroll
    for (int w = 1; w < 64; w <<= 1) { ps_ += __shfl_xor(ps_, w); pp_ += __shfl_xor(pp_, w); }
    float nms = fmaxf(Ms, ps_);
    float fs = __expf(Ms - nms), ws_ = __expf(ps_ - nms);
    Ss = Ss * fs + ws_; ags = ags * fs + ws_ * cs; Ms = nms;
    float nmp = fmaxf(Mp, pp_);
    float fp = __expf(Mp - nmp), wp_ = __expf(pp_ - nmp);
    Sp = Sp * fp + wp_; agp = agp * fp + wp_ * cp; Mp = nmp;
  };

  float s0c, s0d, s1c, s1d;
  {
    int i0 = csr_src[p0];
    s0c = C2s[(size_t)i0 * 128 + lane]; s0d = C2p[(size_t)i0 * 128 + lane];
    if (deg > 1) { int i1 = csr_src[p0 + 1]; s1c = C2s[(size_t)i1 * 128 + lane]; s1d = C2p[(size_t)i1 * 128 + lane]; }
  }
  int p = p0;
  for (; p + 3 < pe; p += 2) {
    int ia = csr_src[p + 2], ib = csr_src[p + 3];
    float n0c = C2s[(size_t)ia * 128 + lane], n0d = C2p[(size_t)ia * 128 + lane];
    float n1c = C2s[(size_t)ib * 128 + lane], n1d = C2p[(size_t)ib * 128 + lane];
    compute(s0c, s0d);
    compute(s1c, s1d);
    s0c = n0c; s0d = n0d; s1c = n1c; s1d = n1d;
  }
  int r = pe - p;                                // r in {1,2,3}
  if (r == 3) {
    int i = csr_src[p + 2];
    float tc = C2s[(size_t)i * 128 + lane], td = C2p[(size_t)i * 128 + lane];
    compute(s0c, s0d); compute(s1c, s1d); compute(tc, td);
  } else if (r == 2) {
    compute(s0c, s0d); compute(s1c, s1d);
  } else {
    compute(s0c, s0d);
  }

  float vs = ags / Ss + b_s[lane];
  float vp = agp / Sp + b_p[lane];
  if (lane < 32) {
    out[(size_t)n * 64 + lane] = vs;
    out[(size_t)n * 64 + 32 + lane] = vp;
  } else {
    float sps = fmaxf(vs, 0.f) + log1pf(__expf(-fabsf(vs))) + 1e-6f;
    float spp = fmaxf(vp, 0.f) + log1pf(__expf(-fabsf(vp))) + 1e-6f;
    out[(size_t)MU_SZ + n * 64 + (lane - 32)] = sps;
    out[(size_t)MU_SZ + n * 64 + 32 + (lane - 32)] = spp;
  }
}

// ---------------- host ----------------

extern "C" void kernel_launch(void* const* d_in, const int* in_sizes, int n_in,
                              void* d_out, int out_size, void* d_ws, size_t ws_size,
                              hipStream_t stream) {
  const float* x      = (const float*)d_in[0];
  const int*   ei     = (const int*)d_in[1];
  const float* Wl_s1  = (const float*)d_in[2];
  const float* Wr_s1  = (const float*)d_in[3];
  const float* att_s1 = (const float*)d_in[4];
  const float* b_s1   = (const float*)d_in[5];
  const float* Wl_s2  = (const float*)d_in[6];
  const float* Wr_s2  = (const float*)d_in[7];
  const float* att_s2 = (const float*)d_in[8];
  const float* b_s2   = (const float*)d_in[9];
  const float* Wl_p1  = (const float*)d_in[10];
  const float* Wr_p1  = (const float*)d_in[11];
  const float* att_p1 = (const float*)d_in[12];
  const float* b_p1   = (const float*)d_in[13];
  const float* Wl_p2  = (const float*)d_in[14];
  const float* Wr_p2  = (const float*)d_in[15];
  const float* att_p2 = (const float*)d_in[16];
  const float* b_p2   = (const float*)d_in[17];

  char* ws = (char*)d_ws;
  unsigned short* Xb   = (unsigned short*)(ws + 0);           // 20224*3072*2 = 124,256,256
  unsigned short* A2s  = (unsigned short*)(ws + 0);           // 20096*512*2 = 20,578,304 (after Xb dead)
  unsigned short* A2p  = (unsigned short*)(ws + 20578304);    // 20,578,304
  float*          C2s  = (float*)(ws + 41156608);             // 10,240,000
  float*          C2p  = (float*)(ws + 51396608);             // 10,240,000
  unsigned short* B2s  = (unsigned short*)(ws + 61636608);    // 131,072 (aliases Xb; written post-gemm256)
  unsigned short* B2p  = (unsigned short*)(ws + 61767680);    // 131,072
  unsigned short* Wp   = (unsigned short*)(ws + 124256256);   // 12,582,912
  unsigned short* XL1  = (unsigned short*)(ws + 136839168);   // 20224*2048*2 = 82,837,504
  int* counts  = (int*)(ws + 219676672);                      // 80,000
  int* row_ptr = (int*)(ws + 219836672);                      // 80,004
  int* csr_src = (int*)(ws + 219916688);                      // 1,360,000

  hipMemsetAsync(counts, 0, NN * sizeof(int), stream);

  k_prep<<<PB_CVT, 256, 0, stream>>>(x, Xb, Wl_s1, Wr_s1, Wl_p1, Wr_p1, Wp, ei, counts);
  k_scan<<<1, 1024, 0, stream>>>(counts, row_ptr);
  k_scatter<<<(ETOT + 255) / 256, 256, 0, stream>>>(ei, row_ptr, counts, csr_src);

  // XL1[n, 0:512|512:1024|1024:1536|1536:2048] = x@{Wl_s1|Wr_s1|Wl_p1|Wr_p1}, bf16
  gemm256<<<632, 512, 0, stream>>>(Xb, Wp, XL1);

  k_pack_w2b<<<512, 256, 0, stream>>>(Wl_s2, Wr_s2, Wl_p2, Wr_p2, B2s, B2p);

  edge_agg1<<<5000, 256, 0, stream>>>(XL1, row_ptr, csr_src, att_s1, att_p1, b_s1, b_p1, A2s, A2p);

  gemm_l2<<<dim3(157, 2), 256, 0, stream>>>(A2s, B2s, C2s, A2p, B2p, C2p);

  edge_agg2<<<5000, 256, 0, stream>>>(C2s, C2p, row_ptr, csr_src, att_s2, att_p2, b_s2, b_p2, (float*)d_out);
}

// Round 17
// 555.262 us; speedup vs baseline: 1.1311x; 1.0358x over previous
//
#include <hip/hip_runtime.h>
#include <cstdint>

// Problem constants
#define NN     20000      // nodes
#define NE     320000     // input edges
#define ETOT   340000     // edges + self loops
#define K1R    3000       // in_dim
#define K1     3072       // padded K for GEMM1
#define NPAD   20224      // 79*256 padded rows (256-tile GEMM1)
#define NCOL1  2048       // packed outputs, NEW order: [xl_s|xl_p|xr_s|xr_p]
#define LDA2   512        // layer-2 A row (plain bf16)
#define MU_SZ  1280000    // 20000*64

typedef __bf16 bf16x8 __attribute__((ext_vector_type(8)));
typedef float f32x4 __attribute__((ext_vector_type(4)));
typedef unsigned short u16x8 __attribute__((ext_vector_type(8)));

__device__ inline unsigned short f2bf(float f) {
  union { float f; unsigned u; } v; v.f = f;
  unsigned r = v.u + 0x7FFFu + ((v.u >> 16) & 1u);
  return (unsigned short)(r >> 16);
}
__device__ inline float bf2f(unsigned short h) {
  union { unsigned u; float f; } v; v.u = ((unsigned)h) << 16;
  return v.f;
}

typedef const __attribute__((address_space(1))) void* gas1_t;
typedef __attribute__((address_space(3))) void* las3_t;
__device__ inline void llds16(const void* g, void* l) {
  __builtin_amdgcn_global_load_lds((gas1_t)(uintptr_t)g,
                                   (las3_t)(uint32_t)(uintptr_t)l, 16, 0, 0);
}

// ---------------- mega-prep: pack_w1 | count | convert_x in one launch ----------
// pack_w1 W-order (host): W0=Wl_s1, W1=Wl_p1, W2=Wr_s1, W3=Wr_p1 -> XL1 cols
// [0:512)=xl_s [512:1024)=xl_p [1024:1536)=xr_s [1536:2048)=xr_p  (edge gathers
// xl_s+xl_p land contiguous: [src*4KB, src*4KB+2KB)).
#define PB_PW1  1536                       // pack_w1: 48 x 32 blocks
#define PB_CNT  (PB_PW1 + 1329)            // count: ceil(ETOT/256)
#define PB_CVT  (PB_CNT + 30336)           // convert: NPAD*384/256

__global__ __launch_bounds__(256)
void k_prep(const float* __restrict__ X, unsigned short* __restrict__ Xb,
            const float* __restrict__ W0, const float* __restrict__ W1,
            const float* __restrict__ W2, const float* __restrict__ W3,
            unsigned short* __restrict__ Wp,
            const int* __restrict__ ei, int* __restrict__ counts) {
  __shared__ float tile[64][65];
  int b = blockIdx.x, tid = threadIdx.x;

  if (b < PB_PW1) {
    int k0 = (b % 48) * 64, n0 = (b / 48) * 64;
    int m = n0 >> 9, c0 = n0 & 511;
    const float* W = (m == 0) ? W0 : (m == 1) ? W1 : (m == 2) ? W2 : W3;
    int tx = tid & 63, ty = tid >> 6;
#pragma unroll
    for (int rep = 0; rep < 16; rep++) {
      int i = ty + rep * 4;
      int k = k0 + i;
      tile[i][tx] = (k < K1R) ? W[(size_t)k * 512 + c0 + tx] : 0.f;
    }
    __syncthreads();
#pragma unroll
    for (int rep = 0; rep < 16; rep++) {
      int i = ty + rep * 4;
      Wp[(size_t)(n0 + i) * K1 + k0 + tx] = f2bf(tile[tx][i]);
    }
  } else if (b < PB_CNT) {
    int e = (b - PB_PW1) * 256 + tid;
    if (e < ETOT) {
      int dst = (e < NE) ? ei[NE + e] : (e - NE);
      atomicAdd(&counts[dst], 1);
    }
  } else {
    const int CH = K1 / 8;
    int idx = (b - PB_CNT) * 256 + tid;
    if (idx >= NPAD * CH) return;
    int r = idx / CH, c8 = (idx % CH) * 8;
    u16x8 o;
    if (r < NN && c8 < K1R) {
      const float4* p = (const float4*)(X + (size_t)r * K1R + c8);
      float4 a = p[0], bb = p[1];
      o[0]=f2bf(a.x); o[1]=f2bf(a.y); o[2]=f2bf(a.z); o[3]=f2bf(a.w);
      o[4]=f2bf(bb.x); o[5]=f2bf(bb.y); o[6]=f2bf(bb.z); o[7]=f2bf(bb.w);
    } else {
#pragma unroll
      for (int j = 0; j < 8; j++) o[j] = 0;
    }
    *(u16x8*)(Xb + (size_t)r * K1 + c8) = o;
  }
}

// ---------------- post-GEMM: scatter (blocks 0..1328) + pack_w2b (1329..1840) ----------
// B2 aliases Xb; safe here because this launches after gemm256 consumed Xb.

#define POST_SCT 1329
#define POST_TOT (POST_SCT + 512)

__global__ __launch_bounds__(256)
void k_post(const int* __restrict__ ei, const int* __restrict__ row_ptr,
            int* __restrict__ counts, int* __restrict__ csr_src,
            const float* __restrict__ Wl_s2, const float* __restrict__ Wr_s2,
            const float* __restrict__ Wl_p2, const float* __restrict__ Wr_p2,
            unsigned short* __restrict__ B2s, unsigned short* __restrict__ B2p) {
  int b = blockIdx.x, tid = threadIdx.x;
  if (b < POST_SCT) {
    int e = b * 256 + tid;
    if (e >= ETOT) return;
    int s_, d_;
    if (e < NE) { s_ = ei[e]; d_ = ei[NE + e]; } else { s_ = d_ = e - NE; }
    int old = atomicSub(&counts[d_], 1);
    csr_src[row_ptr[d_] + old - 1] = s_;
  } else {
    int gidx = (b - POST_SCT) * 256 + tid;
    int br = gidx >> 16, idx = gidx & 65535;
    const float* Wl = br ? Wl_p2 : Wl_s2;
    const float* Wr = br ? Wr_p2 : Wr_s2;
    unsigned short* B2 = br ? B2p : B2s;
    int n = idx >> 9, k = idx & 511;
    float v = (n < 64) ? Wl[(size_t)k * 64 + n] : Wr[(size_t)k * 64 + (n - 64)];
    B2[idx] = f2bf(v);
  }
}

// ---------------- GEMM1: 256x256, role-staggered waves, 1 barrier per K-tile ----------------
// (best measured variant: R6, 293-303 us — FROZEN). Block 632 runs the CSR scan
// (512-thread variant; block-uniform branch; reuses the gemm LDS).

#define NT1 48

#define STAGE_ONE do { \
  if (sctr < 4 * NT1) { \
    int ts_ = sctr >> 2, u_ = sctr & 3, sb_ = ts_ & 1; \
    const unsigned short* gb_; char* lb_; int rb_; \
    if (u_ == 0)      { gb_ = A; rb_ = bmBase + 128; lb_ = lds + (sb_*2+1)*16384; } \
    else if (u_ == 1) { gb_ = B; rb_ = bnBase + 128; lb_ = lds + 65536 + (sb_*2+1)*16384; } \
    else if (u_ == 2) { gb_ = B; rb_ = bnBase;       lb_ = lds + 65536 + (sb_*2+0)*16384; } \
    else              { gb_ = A; rb_ = bmBase;       lb_ = lds + (sb_*2+0)*16384; } \
    const unsigned short* g0_ = gb_ + (size_t)(rb_ + trow) * 3072 + ts_ * 64 + scol; \
    llds16(g0_, lb_ + wid * 1024); \
    llds16(g0_ + (size_t)64 * 3072, lb_ + 8192 + wid * 1024); \
    sctr++; \
  } \
} while (0)

#define RDA(DST, BASE) do { \
  _Pragma("unroll") \
  for (int mi = 0; mi < 2; mi++) { \
    int r_ = rw * 32 + mi * 16 + l15; \
    DST[0][mi] = *(const bf16x8*)((BASE) + r_ * 128 + sw0); \
    DST[1][mi] = *(const bf16x8*)((BASE) + r_ * 128 + sw1); \
  } \
} while (0)

#define RDB(DST, BASE) do { \
  _Pragma("unroll") \
  for (int ni = 0; ni < 4; ni++) { \
    int r_ = cw * 64 + ni * 16 + l15; \
    DST[0][ni] = *(const bf16x8*)((BASE) + r_ * 128 + sw0); \
    DST[1][ni] = *(const bf16x8*)((BASE) + r_ * 128 + sw1); \
  } \
} while (0)

#define MF(MH, NH, AV, BV) do { \
  __builtin_amdgcn_s_setprio(1); \
  _Pragma("unroll") \
  for (int mi = 0; mi < 2; mi++) \
    _Pragma("unroll") \
    for (int ni = 0; ni < 4; ni++) { \
      acc[MH][NH][mi][ni] = __builtin_amdgcn_mfma_f32_16x16x32_bf16(AV[0][mi], BV[0][ni], acc[MH][NH][mi][ni], 0, 0, 0); \
      acc[MH][NH][mi][ni] = __builtin_amdgcn_mfma_f32_16x16x32_bf16(AV[1][mi], BV[1][ni], acc[MH][NH][mi][ni], 0, 0, 0); \
    } \
  __builtin_amdgcn_s_setprio(0); \
} while (0)

__global__ __launch_bounds__(512, 2)
void gemm256(const unsigned short* __restrict__ A, const unsigned short* __restrict__ B,
             unsigned short* __restrict__ C,
             const int* __restrict__ counts, int* __restrict__ row_ptr) {
  __shared__ char lds[131072];
  int tid = threadIdx.x, wid = tid >> 6, lane = tid & 63;

  if (blockIdx.x == 632) {
    // ---- CSR exclusive scan (512 threads, 40 nodes each)
    int* part = (int*)lds;
    int base = tid * 40;
    int loc[40];
    int s = 0;
#pragma unroll
    for (int i = 0; i < 40; i++) {
      int idx = base + i;
      loc[i] = s;
      s += (idx < NN) ? counts[idx] : 0;
    }
    part[tid] = s;
    __syncthreads();
    for (int off = 1; off < 512; off <<= 1) {
      int v = (tid >= off) ? part[tid - off] : 0;
      __syncthreads();
      part[tid] += v;
      __syncthreads();
    }
    int pre = (tid > 0) ? part[tid - 1] : 0;
#pragma unroll
    for (int i = 0; i < 40; i++) {
      int idx = base + i;
      if (idx <= NN) row_ptr[idx] = pre + loc[i];
    }
    return;
  }

  int l15 = lane & 15;
  int rw = wid & 3, cw = wid >> 2;
  int role = (wid >> 2) & 1;
  int bid = blockIdx.x;
  int bn = bid & 7, bm = bid >> 3;
  int bmBase = bm * 256, bnBase = bn * 256;
  int trow = tid >> 3;
  int scol = ((tid & 7) ^ ((tid >> 3) & 7)) * 8;
  int sw0 = (((lane >> 4) + 0) ^ (lane & 7)) * 16;
  int sw1 = (((lane >> 4) + 4) ^ (lane & 7)) * 16;
  f32x4 acc[2][2][2][4] = {};

  int sctr = 0;
  for (int i = 0; i < 4; i++) STAGE_ONE;
  asm volatile("s_waitcnt vmcnt(0)" ::: "memory");
  __builtin_amdgcn_s_barrier();
  asm volatile("" ::: "memory");

  for (int t = 0; t < NT1; t++) {
    int buf = t & 1;
    const char* A0h = lds + (buf * 2 + 0) * 16384;
    const char* A1h = lds + (buf * 2 + 1) * 16384;
    const char* B0h = lds + 65536 + (buf * 2 + 0) * 16384;
    const char* B1h = lds + 65536 + (buf * 2 + 1) * 16384;
    bf16x8 a0[2][2], a1[2][2], b0[2][4], b1[2][4];

    if (role == 0) {
      STAGE_ONE;
      RDA(a0, A0h); RDB(b0, B0h);
      MF(0, 0, a0, b0);
      STAGE_ONE;
      RDA(a1, A1h);
      MF(1, 0, a1, b0);
      STAGE_ONE;
      RDB(b1, B1h);
      MF(1, 1, a1, b1);
      STAGE_ONE;
      MF(0, 1, a0, b1);
    } else {
      STAGE_ONE;
      RDA(a1, A1h); RDB(b1, B1h);
      MF(1, 1, a1, b1);
      STAGE_ONE;
      RDA(a0, A0h);
      MF(0, 1, a0, b1);
      STAGE_ONE;
      RDB(b0, B0h);
      MF(0, 0, a0, b0);
      STAGE_ONE;
      MF(1, 0, a1, b0);
    }
    asm volatile("s_waitcnt vmcnt(0)" ::: "memory");
    __builtin_amdgcn_s_barrier();
    asm volatile("" ::: "memory");
  }

  unsigned short (*sq)[128] = (unsigned short (*)[128])lds;
#pragma unroll
  for (int mh = 0; mh < 2; mh++)
#pragma unroll
    for (int nh = 0; nh < 2; nh++) {
      __syncthreads();
#pragma unroll
      for (int mi = 0; mi < 2; mi++)
#pragma unroll
        for (int ni = 0; ni < 4; ni++)
#pragma unroll
          for (int r = 0; r < 4; r++)
            sq[rw * 32 + mi * 16 + (lane >> 4) * 4 + r][cw * 64 + ni * 16 + l15] =
                f2bf(acc[mh][nh][mi][ni][r]);
      __syncthreads();
#pragma unroll
      for (int it = 0; it < 4; it++) {
        int idx = it * 512 + tid;
        int row = idx >> 4, ch = idx & 15;
        *(u16x8*)(C + (size_t)(bmBase + mh * 128 + row) * NCOL1 + bnBase + nh * 128 + ch * 8) =
            *(const u16x8*)&sq[row][ch * 8];
      }
    }
}

// ---------------- layer-2 GEMM (128-tile m97 structure), both branches, K=512 ----------------

__global__ __launch_bounds__(256)
void gemm_l2(const unsigned short* __restrict__ As, const unsigned short* __restrict__ Bs,
             float* __restrict__ Cs,
             const unsigned short* __restrict__ Ap, const unsigned short* __restrict__ Bp,
             float* __restrict__ Cp) {
  const int K = LDA2, lda = LDA2, ldb = LDA2, ldc = 128, mreal = NN;
  const unsigned short* A = blockIdx.y ? Ap : As;
  const unsigned short* B = blockIdx.y ? Bp : Bs;
  float* C = blockIdx.y ? Cp : Cs;
  __shared__ char smem_raw[16384];
  unsigned short* sA = (unsigned short*)smem_raw;
  unsigned short* sB = sA + 128 * 32;
  int bm = blockIdx.x;
  int tid = threadIdx.x, wid = tid >> 6, lane = tid & 63;
  int wr = wid >> 1, wc = wid & 1;
  f32x4 acc[4][4] = {};

  int ar = 32 * wid + (lane >> 2);
  int acol = (lane & 3) * 8;
  const unsigned short* Ag = A + (size_t)(bm * 128 + ar) * lda + acol;
  const unsigned short* Bg = B + (size_t)ar * ldb + acol;
  unsigned short* la0 = sA + (wid * 2) * 512;
  unsigned short* lb0 = sB + (wid * 2) * 512;
  int frow = lane & 15, koff = (lane >> 4) * 8;

  for (int kt = 0; kt < K; kt += 32) {
    llds16(Ag + kt, la0);
    llds16(Ag + kt + (size_t)16 * lda, la0 + 512);
    llds16(Bg + kt, lb0);
    llds16(Bg + kt + (size_t)16 * ldb, lb0 + 512);
    __syncthreads();
    bf16x8 af[4], bfr[4];
#pragma unroll
    for (int mi = 0; mi < 4; mi++)
      af[mi] = *(const bf16x8*)(sA + (wr * 64 + mi * 16 + frow) * 32 + koff);
#pragma unroll
    for (int ni = 0; ni < 4; ni++)
      bfr[ni] = *(const bf16x8*)(sB + (wc * 64 + ni * 16 + frow) * 32 + koff);
#pragma unroll
    for (int mi = 0; mi < 4; mi++)
#pragma unroll
      for (int ni = 0; ni < 4; ni++)
        acc[mi][ni] = __builtin_amdgcn_mfma_f32_16x16x32_bf16(af[mi], bfr[ni], acc[mi][ni], 0, 0, 0);
    __syncthreads();
  }

#pragma unroll
  for (int mi = 0; mi < 4; mi++) {
    int grow0 = bm * 128 + wr * 64 + mi * 16 + (lane >> 4) * 4;
#pragma unroll
    for (int ni = 0; ni < 4; ni++) {
      int gcol = wc * 64 + ni * 16 + (lane & 15);
#pragma unroll
      for (int r = 0; r < 4; r++) {
        int grow = grow0 + r;
        if (grow < mreal) C[(size_t)grow * ldc + gcol] = acc[mi][ni][r];
      }
    }
  }
}

// ---------------- layer-1 edge agg: both branches per wave, depth-2 unconditional pipeline ----
// XL1 layout: [xl_s|xl_p|xr_s|xr_p]; per-edge gathers contiguous [src*4KB, +2KB).

__global__ __launch_bounds__(256)
void edge_agg1(const unsigned short* __restrict__ XL1,
               const int* __restrict__ row_ptr, const int* __restrict__ csr_src,
               const float* __restrict__ att_s, const float* __restrict__ att_p,
               const float* __restrict__ b_s, const float* __restrict__ b_p,
               unsigned short* __restrict__ A2s, unsigned short* __restrict__ A2p) {
  int n = (blockIdx.x * 256 + threadIdx.x) >> 6;
  if (n >= NN) return;
  int lane = threadIdx.x & 63;
  int cb = lane * 8;
  float xs[8], xp[8], as_[8], ap_[8], aggs[8], aggp[8];
  {
    bf16x8 xsv = *(const bf16x8*)(XL1 + (size_t)n * NCOL1 + 1024 + cb);   // xr_s
    bf16x8 xpv = *(const bf16x8*)(XL1 + (size_t)n * NCOL1 + 1536 + cb);   // xr_p
    float4 a0 = *(const float4*)(att_s + cb), a1 = *(const float4*)(att_s + cb + 4);
    float4 a2 = *(const float4*)(att_p + cb), a3 = *(const float4*)(att_p + cb + 4);
    as_[0]=a0.x; as_[1]=a0.y; as_[2]=a0.z; as_[3]=a0.w; as_[4]=a1.x; as_[5]=a1.y; as_[6]=a1.z; as_[7]=a1.w;
    ap_[0]=a2.x; ap_[1]=a2.y; ap_[2]=a2.z; ap_[3]=a2.w; ap_[4]=a3.x; ap_[5]=a3.y; ap_[6]=a3.z; ap_[7]=a3.w;
#pragma unroll
    for (int j = 0; j < 8; j++) { xs[j] = (float)xsv[j]; xp[j] = (float)xpv[j]; aggs[j] = 0.f; aggp[j] = 0.f; }
  }
  float Ms = -1e30f, Ss = 0.f, Mp = -1e30f, Sp = 0.f;
  int p0 = row_ptr[n], pe = row_ptr[n + 1];
  int deg = pe - p0;

  auto gS = [&](int s) { return *(const bf16x8*)(XL1 + (size_t)s * NCOL1 + cb); };        // xl_s
  auto gP = [&](int s) { return *(const bf16x8*)(XL1 + (size_t)s * NCOL1 + 512 + cb); };  // xl_p
  auto compute = [&](bf16x8 cs, bf16x8 cp) {
    float mjs[8], mjp[8], ps_ = 0.f, pp_ = 0.f;
#pragma unroll
    for (int j = 0; j < 8; j++) {
      mjs[j] = (float)cs[j];
      float t = mjs[j] + xs[j];
      t = (t > 0.f) ? t : 0.2f * t;
      ps_ = fmaf(as_[j], t, ps_);
      mjp[j] = (float)cp[j];
      float u = mjp[j] + xp[j];
      u = (u > 0.f) ? u : 0.2f * u;
      pp_ = fmaf(ap_[j], u, pp_);
    }
#pragma unroll
    for (int w = 1; w < 16; w <<= 1) { ps_ += __shfl_xor(ps_, w); pp_ += __shfl_xor(pp_, w); }
    float nms = fmaxf(Ms, ps_);
    float fs = __expf(Ms - nms), ws_ = __expf(ps_ - nms);
    Ss = Ss * fs + ws_;
    float nmp = fmaxf(Mp, pp_);
    float fp = __expf(Mp - nmp), wp_ = __expf(pp_ - nmp);
    Sp = Sp * fp + wp_;
#pragma unroll
    for (int j = 0; j < 8; j++) {
      aggs[j] = aggs[j] * fs + ws_ * mjs[j];
      aggp[j] = aggp[j] * fp + wp_ * mjp[j];
    }
    Ms = nms; Mp = nmp;
  };

  bf16x8 s0s, s0p, s1s, s1p;
  {
    int i0 = csr_src[p0];
    s0s = gS(i0); s0p = gP(i0);
    if (deg > 1) { int i1 = csr_src[p0 + 1]; s1s = gS(i1); s1p = gP(i1); }
  }
  int p = p0;
  for (; p + 3 < pe; p += 2) {
    int ia = csr_src[p + 2], ib = csr_src[p + 3];
    bf16x8 n0s = gS(ia), n0p = gP(ia);
    bf16x8 n1s = gS(ib), n1p = gP(ib);
    compute(s0s, s0p);
    compute(s1s, s1p);
    s0s = n0s; s0p = n0p; s1s = n1s; s1p = n1p;
  }
  int r = pe - p;                                // r in {1,2,3}
  if (r == 3) {
    int i = csr_src[p + 2];
    bf16x8 ts = gS(i), tp = gP(i);
    compute(s0s, s0p); compute(s1s, s1p); compute(ts, tp);
  } else if (r == 2) {
    compute(s0s, s0p); compute(s1s, s1p);
  } else {
    compute(s0s, s0p);
  }

  float invs = 1.f / Ss, invp = 1.f / Sp;
  u16x8 hs, hp;
#pragma unroll
  for (int j = 0; j < 8; j++) {
    float v = fmaxf(aggs[j] * invs + b_s[cb + j], 0.f);
    hs[j] = f2bf(v);
    float u = aggp[j] * invp + b_p[cb + j];
    hp[j] = f2bf(u);
  }
  *(u16x8*)(A2s + (size_t)n * LDA2 + cb) = hs;
  *(u16x8*)(A2p + (size_t)n * LDA2 + cb) = hp;
}

// ---------------- layer-2 edge agg + epilogue: both branches per wave, depth-2 pipeline ----

__global__ __launch_bounds__(256)
void edge_agg2(const float* __restrict__ C2s, const float* __restrict__ C2p,
               const int* __restrict__ row_ptr, const int* __restrict__ csr_src,
               const float* __restrict__ att_s, const float* __restrict__ att_p,
               const float* __restrict__ b_s, const float* __restrict__ b_p,
               float* __restrict__ out) {
  int n = (blockIdx.x * 256 + threadIdx.x) >> 6;
  if (n >= NN) return;
  int lane = threadIdx.x & 63;
  float xrs = C2s[(size_t)n * 128 + 64 + lane];
  float xrp = C2p[(size_t)n * 128 + 64 + lane];
  float ats = att_s[lane], atp = att_p[lane];
  float Ms = -1e30f, Ss = 0.f, ags = 0.f;
  float Mp = -1e30f, Sp = 0.f, agp = 0.f;
  int p0 = row_ptr[n], pe = row_ptr[n + 1];
  int deg = pe - p0;

  auto compute = [&](float cs, float cp) {
    float t = cs + xrs; t = (t > 0.f) ? t : 0.2f * t;
    float u = cp + xrp; u = (u > 0.f) ? u : 0.2f * u;
    float ps_ = ats * t, pp_ = atp * u;
#pragma unroll
    for (int w = 1; w < 64; w <<= 1) { ps_ += __shfl_xor(ps_, w); pp_ += __shfl_xor(pp_, w); }
    float nms = fmaxf(Ms, ps_);
    float fs = __expf(Ms - nms), ws_ = __expf(ps_ - nms);
    Ss = Ss * fs + ws_; ags = ags * fs + ws_ * cs; Ms = nms;
    float nmp = fmaxf(Mp, pp_);
    float fp = __expf(Mp - nmp), wp_ = __expf(pp_ - nmp);
    Sp = Sp * fp + wp_; agp = agp * fp + wp_ * cp; Mp = nmp;
  };

  float s0c, s0d, s1c, s1d;
  {
    int i0 = csr_src[p0];
    s0c = C2s[(size_t)i0 * 128 + lane]; s0d = C2p[(size_t)i0 * 128 + lane];
    if (deg > 1) { int i1 = csr_src[p0 + 1]; s1c = C2s[(size_t)i1 * 128 + lane]; s1d = C2p[(size_t)i1 * 128 + lane]; }
  }
  int p = p0;
  for (; p + 3 < pe; p += 2) {
    int ia = csr_src[p + 2], ib = csr_src[p + 3];
    float n0c = C2s[(size_t)ia * 128 + lane], n0d = C2p[(size_t)ia * 128 + lane];
    float n1c = C2s[(size_t)ib * 128 + lane], n1d = C2p[(size_t)ib * 128 + lane];
    compute(s0c, s0d);
    compute(s1c, s1d);
    s0c = n0c; s0d = n0d; s1c = n1c; s1d = n1d;
  }
  int r = pe - p;                                // r in {1,2,3}
  if (r == 3) {
    int i = csr_src[p + 2];
    float tc = C2s[(size_t)i * 128 + lane], td = C2p[(size_t)i * 128 + lane];
    compute(s0c, s0d); compute(s1c, s1d); compute(tc, td);
  } else if (r == 2) {
    compute(s0c, s0d); compute(s1c, s1d);
  } else {
    compute(s0c, s0d);
  }

  float vs = ags / Ss + b_s[lane];
  float vp = agp / Sp + b_p[lane];
  if (lane < 32) {
    out[(size_t)n * 64 + lane] = vs;
    out[(size_t)n * 64 + 32 + lane] = vp;
  } else {
    float sps = fmaxf(vs, 0.f) + log1pf(__expf(-fabsf(vs))) + 1e-6f;
    float spp = fmaxf(vp, 0.f) + log1pf(__expf(-fabsf(vp))) + 1e-6f;
    out[(size_t)MU_SZ + n * 64 + (lane - 32)] = sps;
    out[(size_t)MU_SZ + n * 64 + 32 + (lane - 32)] = spp;
  }
}

// ---------------- host ----------------

extern "C" void kernel_launch(void* const* d_in, const int* in_sizes, int n_in,
                              void* d_out, int out_size, void* d_ws, size_t ws_size,
                              hipStream_t stream) {
  const float* x      = (const float*)d_in[0];
  const int*   ei     = (const int*)d_in[1];
  const float* Wl_s1  = (const float*)d_in[2];
  const float* Wr_s1  = (const float*)d_in[3];
  const float* att_s1 = (const float*)d_in[4];
  const float* b_s1   = (const float*)d_in[5];
  const float* Wl_s2  = (const float*)d_in[6];
  const float* Wr_s2  = (const float*)d_in[7];
  const float* att_s2 = (const float*)d_in[8];
  const float* b_s2   = (const float*)d_in[9];
  const float* Wl_p1  = (const float*)d_in[10];
  const float* Wr_p1  = (const float*)d_in[11];
  const float* att_p1 = (const float*)d_in[12];
  const float* b_p1   = (const float*)d_in[13];
  const float* Wl_p2  = (const float*)d_in[14];
  const float* Wr_p2  = (const float*)d_in[15];
  const float* att_p2 = (const float*)d_in[16];
  const float* b_p2   = (const float*)d_in[17];

  char* ws = (char*)d_ws;
  unsigned short* Xb   = (unsigned short*)(ws + 0);           // 20224*3072*2 = 124,256,256
  unsigned short* A2s  = (unsigned short*)(ws + 0);           // 20096*512*2 = 20,578,304 (after Xb dead)
  unsigned short* A2p  = (unsigned short*)(ws + 20578304);    // 20,578,304
  float*          C2s  = (float*)(ws + 41156608);             // 10,240,000
  float*          C2p  = (float*)(ws + 51396608);             // 10,240,000
  unsigned short* B2s  = (unsigned short*)(ws + 61636608);    // 131,072 (aliases Xb; written post-gemm256)
  unsigned short* B2p  = (unsigned short*)(ws + 61767680);    // 131,072
  unsigned short* Wp   = (unsigned short*)(ws + 124256256);   // 12,582,912
  unsigned short* XL1  = (unsigned short*)(ws + 136839168);   // 20224*2048*2 = 82,837,504
  int* counts  = (int*)(ws + 219676672);                      // 80,000
  int* row_ptr = (int*)(ws + 219836672);                      // 80,004
  int* csr_src = (int*)(ws + 219916688);                      // 1,360,000

  hipMemsetAsync(counts, 0, NN * sizeof(int), stream);

  // W order gives XL1 = [xl_s | xl_p | xr_s | xr_p]
  k_prep<<<PB_CVT, 256, 0, stream>>>(x, Xb, Wl_s1, Wl_p1, Wr_s1, Wr_p1, Wp, ei, counts);

  // gemm256 + embedded CSR scan (block 632)
  gemm256<<<633, 512, 0, stream>>>(Xb, Wp, XL1, counts, row_ptr);

  // scatter + pack_w2b (B2 aliases Xb; safe post-gemm)
  k_post<<<POST_TOT, 256, 0, stream>>>(ei, row_ptr, counts, csr_src,
                                       Wl_s2, Wr_s2, Wl_p2, Wr_p2, B2s, B2p);

  edge_agg1<<<5000, 256, 0, stream>>>(XL1, row_ptr, csr_src, att_s1, att_p1, b_s1, b_p1, A2s, A2p);

  gemm_l2<<<dim3(157, 2), 256, 0, stream>>>(A2s, B2s, C2s, A2p, B2p, C2p);

  edge_agg2<<<5000, 256, 0, stream>>>(C2s, C2p, row_ptr, csr_src, att_s2, att_p2, b_s2, b_p2, (float*)d_out);
}

// Round 18
// 555.107 us; speedup vs baseline: 1.1314x; 1.0003x over previous
//
#include <hip/hip_runtime.h>
#include <cstdint>

// Problem constants
#define NN     20000      // nodes
#define NE     320000     // input edges
#define ETOT   340000     // edges + self loops
#define K1R    3000       // in_dim
#define K1     3072       // padded K for GEMM1
#define NPAD   20224      // 79*256 padded rows (256-tile GEMM1)
#define NCOL1  2048       // packed outputs: [xl_s|xl_p|xr_s|xr_p]
#define LDA2   512        // layer-2 A row (plain bf16)
#define MU_SZ  1280000    // 20000*64

typedef __bf16 bf16x8 __attribute__((ext_vector_type(8)));
typedef float f32x4 __attribute__((ext_vector_type(4)));
typedef unsigned short u16x8 __attribute__((ext_vector_type(8)));

__device__ inline unsigned short f2bf(float f) {
  union { float f; unsigned u; } v; v.f = f;
  unsigned r = v.u + 0x7FFFu + ((v.u >> 16) & 1u);
  return (unsigned short)(r >> 16);
}
__device__ inline float bf2f(unsigned short h) {
  union { unsigned u; float f; } v; v.u = ((unsigned)h) << 16;
  return v.f;
}

typedef const __attribute__((address_space(1))) void* gas1_t;
typedef __attribute__((address_space(3))) void* las3_t;
__device__ inline void llds16(const void* g, void* l) {
  __builtin_amdgcn_global_load_lds((gas1_t)(uintptr_t)g,
                                   (las3_t)(uint32_t)(uintptr_t)l, 16, 0, 0);
}

// ---------------- mega-prep: pack_w1 | count | convert_x in one launch ----------
// pack_w1 W-order (host): Wl_s1, Wl_p1, Wr_s1, Wr_p1 -> XL1 = [xl_s|xl_p|xr_s|xr_p].
#define PB_PW1  1536                       // pack_w1: 48 x 32 blocks
#define PB_CNT  (PB_PW1 + 1329)            // count: ceil(ETOT/256)
#define PB_CVT  (PB_CNT + 30336)           // convert: NPAD*384/256

__global__ __launch_bounds__(256)
void k_prep(const float* __restrict__ X, unsigned short* __restrict__ Xb,
            const float* __restrict__ W0, const float* __restrict__ W1,
            const float* __restrict__ W2, const float* __restrict__ W3,
            unsigned short* __restrict__ Wp,
            const int* __restrict__ ei, int* __restrict__ counts) {
  __shared__ float tile[64][65];
  int b = blockIdx.x, tid = threadIdx.x;

  if (b < PB_PW1) {
    int k0 = (b % 48) * 64, n0 = (b / 48) * 64;
    int m = n0 >> 9, c0 = n0 & 511;
    const float* W = (m == 0) ? W0 : (m == 1) ? W1 : (m == 2) ? W2 : W3;
    int tx = tid & 63, ty = tid >> 6;
#pragma unroll
    for (int rep = 0; rep < 16; rep++) {
      int i = ty + rep * 4;
      int k = k0 + i;
      tile[i][tx] = (k < K1R) ? W[(size_t)k * 512 + c0 + tx] : 0.f;
    }
    __syncthreads();
#pragma unroll
    for (int rep = 0; rep < 16; rep++) {
      int i = ty + rep * 4;
      Wp[(size_t)(n0 + i) * K1 + k0 + tx] = f2bf(tile[tx][i]);
    }
  } else if (b < PB_CNT) {
    int e = (b - PB_PW1) * 256 + tid;
    if (e < ETOT) {
      int dst = (e < NE) ? ei[NE + e] : (e - NE);
      atomicAdd(&counts[dst], 1);
    }
  } else {
    const int CH = K1 / 8;
    int idx = (b - PB_CNT) * 256 + tid;
    if (idx >= NPAD * CH) return;
    int r = idx / CH, c8 = (idx % CH) * 8;
    u16x8 o;
    if (r < NN && c8 < K1R) {
      const float4* p = (const float4*)(X + (size_t)r * K1R + c8);
      float4 a = p[0], bb = p[1];
      o[0]=f2bf(a.x); o[1]=f2bf(a.y); o[2]=f2bf(a.z); o[3]=f2bf(a.w);
      o[4]=f2bf(bb.x); o[5]=f2bf(bb.y); o[6]=f2bf(bb.z); o[7]=f2bf(bb.w);
    } else {
#pragma unroll
      for (int j = 0; j < 8; j++) o[j] = 0;
    }
    *(u16x8*)(Xb + (size_t)r * K1 + c8) = o;
  }
}

// ---------------- standalone CSR scan (must precede gemm256+scatter grid) ----------

__global__ void k_scan(const int* __restrict__ counts, int* __restrict__ row_ptr) {
  __shared__ int part[1024];
  int t = threadIdx.x;
  int base = t * 20;
  int loc[20];
  int s = 0;
#pragma unroll
  for (int i = 0; i < 20; i++) {
    int idx = base + i;
    loc[i] = s;
    s += (idx < NN) ? counts[idx] : 0;
  }
  part[t] = s;
  __syncthreads();
  for (int off = 1; off < 1024; off <<= 1) {
    int v = (t >= off) ? part[t - off] : 0;
    __syncthreads();
    part[t] += v;
    __syncthreads();
  }
  int pre = (t > 0) ? part[t - 1] : 0;
#pragma unroll
  for (int i = 0; i < 20; i++) {
    int idx = base + i;
    if (idx <= NN) row_ptr[idx] = pre + loc[i];
  }
}

// ---------------- GEMM1: 256x256, role-staggered waves (FROZEN) + scatter tail blocks ----
// Blocks 0..631: gemm tiles. Blocks 632..1296: CSR scatter (fills round-3 idle CUs).
// Scatter needs row_ptr (ready: k_scan precedes this launch on the stream).

#define NT1 48
#define G_SCT 632
#define G_TOT (G_SCT + 665)   // 665 = ceil(340000/512)

#define STAGE_ONE do { \
  if (sctr < 4 * NT1) { \
    int ts_ = sctr >> 2, u_ = sctr & 3, sb_ = ts_ & 1; \
    const unsigned short* gb_; char* lb_; int rb_; \
    if (u_ == 0)      { gb_ = A; rb_ = bmBase + 128; lb_ = lds + (sb_*2+1)*16384; } \
    else if (u_ == 1) { gb_ = B; rb_ = bnBase + 128; lb_ = lds + 65536 + (sb_*2+1)*16384; } \
    else if (u_ == 2) { gb_ = B; rb_ = bnBase;       lb_ = lds + 65536 + (sb_*2+0)*16384; } \
    else              { gb_ = A; rb_ = bmBase;       lb_ = lds + (sb_*2+0)*16384; } \
    const unsigned short* g0_ = gb_ + (size_t)(rb_ + trow) * 3072 + ts_ * 64 + scol; \
    llds16(g0_, lb_ + wid * 1024); \
    llds16(g0_ + (size_t)64 * 3072, lb_ + 8192 + wid * 1024); \
    sctr++; \
  } \
} while (0)

#define RDA(DST, BASE) do { \
  _Pragma("unroll") \
  for (int mi = 0; mi < 2; mi++) { \
    int r_ = rw * 32 + mi * 16 + l15; \
    DST[0][mi] = *(const bf16x8*)((BASE) + r_ * 128 + sw0); \
    DST[1][mi] = *(const bf16x8*)((BASE) + r_ * 128 + sw1); \
  } \
} while (0)

#define RDB(DST, BASE) do { \
  _Pragma("unroll") \
  for (int ni = 0; ni < 4; ni++) { \
    int r_ = cw * 64 + ni * 16 + l15; \
    DST[0][ni] = *(const bf16x8*)((BASE) + r_ * 128 + sw0); \
    DST[1][ni] = *(const bf16x8*)((BASE) + r_ * 128 + sw1); \
  } \
} while (0)

#define MF(MH, NH, AV, BV) do { \
  __builtin_amdgcn_s_setprio(1); \
  _Pragma("unroll") \
  for (int mi = 0; mi < 2; mi++) \
    _Pragma("unroll") \
    for (int ni = 0; ni < 4; ni++) { \
      acc[MH][NH][mi][ni] = __builtin_amdgcn_mfma_f32_16x16x32_bf16(AV[0][mi], BV[0][ni], acc[MH][NH][mi][ni], 0, 0, 0); \
      acc[MH][NH][mi][ni] = __builtin_amdgcn_mfma_f32_16x16x32_bf16(AV[1][mi], BV[1][ni], acc[MH][NH][mi][ni], 0, 0, 0); \
    } \
  __builtin_amdgcn_s_setprio(0); \
} while (0)

__global__ __launch_bounds__(512, 2)
void gemm256(const unsigned short* __restrict__ A, const unsigned short* __restrict__ B,
             unsigned short* __restrict__ C,
             const int* __restrict__ ei, const int* __restrict__ row_ptr,
             int* __restrict__ counts, int* __restrict__ csr_src) {
  __shared__ char lds[131072];
  int tid = threadIdx.x, wid = tid >> 6, lane = tid & 63;

  if (blockIdx.x >= G_SCT) {
    // ---- CSR scatter: counts as down-counting cursor
    int e = (blockIdx.x - G_SCT) * 512 + tid;
    if (e >= ETOT) return;
    int s_, d_;
    if (e < NE) { s_ = ei[e]; d_ = ei[NE + e]; } else { s_ = d_ = e - NE; }
    int old = atomicSub(&counts[d_], 1);
    csr_src[row_ptr[d_] + old - 1] = s_;
    return;
  }

  int l15 = lane & 15;
  int rw = wid & 3, cw = wid >> 2;
  int role = (wid >> 2) & 1;
  int bid = blockIdx.x;
  int bn = bid & 7, bm = bid >> 3;
  int bmBase = bm * 256, bnBase = bn * 256;
  int trow = tid >> 3;
  int scol = ((tid & 7) ^ ((tid >> 3) & 7)) * 8;
  int sw0 = (((lane >> 4) + 0) ^ (lane & 7)) * 16;
  int sw1 = (((lane >> 4) + 4) ^ (lane & 7)) * 16;
  f32x4 acc[2][2][2][4] = {};

  int sctr = 0;
  for (int i = 0; i < 4; i++) STAGE_ONE;
  asm volatile("s_waitcnt vmcnt(0)" ::: "memory");
  __builtin_amdgcn_s_barrier();
  asm volatile("" ::: "memory");

  for (int t = 0; t < NT1; t++) {
    int buf = t & 1;
    const char* A0h = lds + (buf * 2 + 0) * 16384;
    const char* A1h = lds + (buf * 2 + 1) * 16384;
    const char* B0h = lds + 65536 + (buf * 2 + 0) * 16384;
    const char* B1h = lds + 65536 + (buf * 2 + 1) * 16384;
    bf16x8 a0[2][2], a1[2][2], b0[2][4], b1[2][4];

    if (role == 0) {
      STAGE_ONE;
      RDA(a0, A0h); RDB(b0, B0h);
      MF(0, 0, a0, b0);
      STAGE_ONE;
      RDA(a1, A1h);
      MF(1, 0, a1, b0);
      STAGE_ONE;
      RDB(b1, B1h);
      MF(1, 1, a1, b1);
      STAGE_ONE;
      MF(0, 1, a0, b1);
    } else {
      STAGE_ONE;
      RDA(a1, A1h); RDB(b1, B1h);
      MF(1, 1, a1, b1);
      STAGE_ONE;
      RDA(a0, A0h);
      MF(0, 1, a0, b1);
      STAGE_ONE;
      RDB(b0, B0h);
      MF(0, 0, a0, b0);
      STAGE_ONE;
      MF(1, 0, a1, b0);
    }
    asm volatile("s_waitcnt vmcnt(0)" ::: "memory");
    __builtin_amdgcn_s_barrier();
    asm volatile("" ::: "memory");
  }

  unsigned short (*sq)[128] = (unsigned short (*)[128])lds;
#pragma unroll
  for (int mh = 0; mh < 2; mh++)
#pragma unroll
    for (int nh = 0; nh < 2; nh++) {
      __syncthreads();
#pragma unroll
      for (int mi = 0; mi < 2; mi++)
#pragma unroll
        for (int ni = 0; ni < 4; ni++)
#pragma unroll
          for (int r = 0; r < 4; r++)
            sq[rw * 32 + mi * 16 + (lane >> 4) * 4 + r][cw * 64 + ni * 16 + l15] =
                f2bf(acc[mh][nh][mi][ni][r]);
      __syncthreads();
#pragma unroll
      for (int it = 0; it < 4; it++) {
        int idx = it * 512 + tid;
        int row = idx >> 4, ch = idx & 15;
        *(u16x8*)(C + (size_t)(bmBase + mh * 128 + row) * NCOL1 + bnBase + nh * 128 + ch * 8) =
            *(const u16x8*)&sq[row][ch * 8];
      }
    }
}

// ---------------- layer-2 GEMM (128-tile m97 structure), interleaved C [n][256]=s|p ----------

__global__ __launch_bounds__(256)
void gemm_l2(const unsigned short* __restrict__ As, const unsigned short* __restrict__ Bs,
             const unsigned short* __restrict__ Ap, const unsigned short* __restrict__ Bp,
             float* __restrict__ C2) {
  const int K = LDA2, lda = LDA2, ldb = LDA2, mreal = NN;
  const unsigned short* A = blockIdx.y ? Ap : As;
  const unsigned short* B = blockIdx.y ? Bp : Bs;
  int colbase = blockIdx.y ? 128 : 0;
  __shared__ char smem_raw[16384];
  unsigned short* sA = (unsigned short*)smem_raw;
  unsigned short* sB = sA + 128 * 32;
  int bm = blockIdx.x;
  int tid = threadIdx.x, wid = tid >> 6, lane = tid & 63;
  int wr = wid >> 1, wc = wid & 1;
  f32x4 acc[4][4] = {};

  int ar = 32 * wid + (lane >> 2);
  int acol = (lane & 3) * 8;
  const unsigned short* Ag = A + (size_t)(bm * 128 + ar) * lda + acol;
  const unsigned short* Bg = B + (size_t)ar * ldb + acol;
  unsigned short* la0 = sA + (wid * 2) * 512;
  unsigned short* lb0 = sB + (wid * 2) * 512;
  int frow = lane & 15, koff = (lane >> 4) * 8;

  for (int kt = 0; kt < K; kt += 32) {
    llds16(Ag + kt, la0);
    llds16(Ag + kt + (size_t)16 * lda, la0 + 512);
    llds16(Bg + kt, lb0);
    llds16(Bg + kt + (size_t)16 * ldb, lb0 + 512);
    __syncthreads();
    bf16x8 af[4], bfr[4];
#pragma unroll
    for (int mi = 0; mi < 4; mi++)
      af[mi] = *(const bf16x8*)(sA + (wr * 64 + mi * 16 + frow) * 32 + koff);
#pragma unroll
    for (int ni = 0; ni < 4; ni++)
      bfr[ni] = *(const bf16x8*)(sB + (wc * 64 + ni * 16 + frow) * 32 + koff);
#pragma unroll
    for (int mi = 0; mi < 4; mi++)
#pragma unroll
      for (int ni = 0; ni < 4; ni++)
        acc[mi][ni] = __builtin_amdgcn_mfma_f32_16x16x32_bf16(af[mi], bfr[ni], acc[mi][ni], 0, 0, 0);
    __syncthreads();
  }

#pragma unroll
  for (int mi = 0; mi < 4; mi++) {
    int grow0 = bm * 128 + wr * 64 + mi * 16 + (lane >> 4) * 4;
#pragma unroll
    for (int ni = 0; ni < 4; ni++) {
      int gcol = colbase + wc * 64 + ni * 16 + (lane & 15);
#pragma unroll
      for (int r = 0; r < 4; r++) {
        int grow = grow0 + r;
        if (grow < mreal) C2[(size_t)grow * 256 + gcol] = acc[mi][ni][r];
      }
    }
  }
}

// ---------------- layer-1 edge agg (blocks 0..4999) + pack_w2b tail (5000..5511) ----------
// XL1 layout: [xl_s|xl_p|xr_s|xr_p]; per-edge gathers contiguous [src*4KB, +2KB).
// pack_w2b here is safe: Xb dead after gemm256; B2 (61.6MB) doesn't overlap A2 (<41.2MB).

#define AG1_N   5000
#define AG1_TOT (AG1_N + 512)

__global__ __launch_bounds__(256)
void edge_agg1(const unsigned short* __restrict__ XL1,
               const int* __restrict__ row_ptr, const int* __restrict__ csr_src,
               const float* __restrict__ att_s, const float* __restrict__ att_p,
               const float* __restrict__ b_s, const float* __restrict__ b_p,
               unsigned short* __restrict__ A2s, unsigned short* __restrict__ A2p,
               const float* __restrict__ Wl_s2, const float* __restrict__ Wr_s2,
               const float* __restrict__ Wl_p2, const float* __restrict__ Wr_p2,
               unsigned short* __restrict__ B2s, unsigned short* __restrict__ B2p) {
  if (blockIdx.x >= AG1_N) {
    int gidx = (blockIdx.x - AG1_N) * 256 + threadIdx.x;   // 0..131071
    int br = gidx >> 16, idx = gidx & 65535;
    const float* Wl = br ? Wl_p2 : Wl_s2;
    const float* Wr = br ? Wr_p2 : Wr_s2;
    unsigned short* B2 = br ? B2p : B2s;
    int n = idx >> 9, k = idx & 511;
    float v = (n < 64) ? Wl[(size_t)k * 64 + n] : Wr[(size_t)k * 64 + (n - 64)];
    B2[idx] = f2bf(v);
    return;
  }
  int n = (blockIdx.x * 256 + threadIdx.x) >> 6;
  if (n >= NN) return;
  int lane = threadIdx.x & 63;
  int cb = lane * 8;
  float xs[8], xp[8], as_[8], ap_[8], aggs[8], aggp[8];
  {
    bf16x8 xsv = *(const bf16x8*)(XL1 + (size_t)n * NCOL1 + 1024 + cb);   // xr_s
    bf16x8 xpv = *(const bf16x8*)(XL1 + (size_t)n * NCOL1 + 1536 + cb);   // xr_p
    float4 a0 = *(const float4*)(att_s + cb), a1 = *(const float4*)(att_s + cb + 4);
    float4 a2 = *(const float4*)(att_p + cb), a3 = *(const float4*)(att_p + cb + 4);
    as_[0]=a0.x; as_[1]=a0.y; as_[2]=a0.z; as_[3]=a0.w; as_[4]=a1.x; as_[5]=a1.y; as_[6]=a1.z; as_[7]=a1.w;
    ap_[0]=a2.x; ap_[1]=a2.y; ap_[2]=a2.z; ap_[3]=a2.w; ap_[4]=a3.x; ap_[5]=a3.y; ap_[6]=a3.z; ap_[7]=a3.w;
#pragma unroll
    for (int j = 0; j < 8; j++) { xs[j] = (float)xsv[j]; xp[j] = (float)xpv[j]; aggs[j] = 0.f; aggp[j] = 0.f; }
  }
  float Ms = -1e30f, Ss = 0.f, Mp = -1e30f, Sp = 0.f;
  int p0 = row_ptr[n], pe = row_ptr[n + 1];
  int deg = pe - p0;

  auto gS = [&](int s) { return *(const bf16x8*)(XL1 + (size_t)s * NCOL1 + cb); };        // xl_s
  auto gP = [&](int s) { return *(const bf16x8*)(XL1 + (size_t)s * NCOL1 + 512 + cb); };  // xl_p
  auto compute = [&](bf16x8 cs, bf16x8 cp) {
    float mjs[8], mjp[8], ps_ = 0.f, pp_ = 0.f;
#pragma unroll
    for (int j = 0; j < 8; j++) {
      mjs[j] = (float)cs[j];
      float t = mjs[j] + xs[j];
      t = (t > 0.f) ? t : 0.2f * t;
      ps_ = fmaf(as_[j], t, ps_);
      mjp[j] = (float)cp[j];
      float u = mjp[j] + xp[j];
      u = (u > 0.f) ? u : 0.2f * u;
      pp_ = fmaf(ap_[j], u, pp_);
    }
#pragma unroll
    for (int w = 1; w < 16; w <<= 1) { ps_ += __shfl_xor(ps_, w); pp_ += __shfl_xor(pp_, w); }
    float nms = fmaxf(Ms, ps_);
    float fs = __expf(Ms - nms), ws_ = __expf(ps_ - nms);
    Ss = Ss * fs + ws_;
    float nmp = fmaxf(Mp, pp_);
    float fp = __expf(Mp - nmp), wp_ = __expf(pp_ - nmp);
    Sp = Sp * fp + wp_;
#pragma unroll
    for (int j = 0; j < 8; j++) {
      aggs[j] = aggs[j] * fs + ws_ * mjs[j];
      aggp[j] = aggp[j] * fp + wp_ * mjp[j];
    }
    Ms = nms; Mp = nmp;
  };

  bf16x8 s0s, s0p, s1s, s1p;
  {
    int i0 = csr_src[p0];
    s0s = gS(i0); s0p = gP(i0);
    if (deg > 1) { int i1 = csr_src[p0 + 1]; s1s = gS(i1); s1p = gP(i1); }
  }
  int p = p0;
  for (; p + 3 < pe; p += 2) {
    int ia = csr_src[p + 2], ib = csr_src[p + 3];
    bf16x8 n0s = gS(ia), n0p = gP(ia);
    bf16x8 n1s = gS(ib), n1p = gP(ib);
    compute(s0s, s0p);
    compute(s1s, s1p);
    s0s = n0s; s0p = n0p; s1s = n1s; s1p = n1p;
  }
  int r = pe - p;                                // r in {1,2,3}
  if (r == 3) {
    int i = csr_src[p + 2];
    bf16x8 ts = gS(i), tp = gP(i);
    compute(s0s, s0p); compute(s1s, s1p); compute(ts, tp);
  } else if (r == 2) {
    compute(s0s, s0p); compute(s1s, s1p);
  } else {
    compute(s0s, s0p);
  }

  float invs = 1.f / Ss, invp = 1.f / Sp;
  u16x8 hs, hp;
#pragma unroll
  for (int j = 0; j < 8; j++) {
    float v = fmaxf(aggs[j] * invs + b_s[cb + j], 0.f);
    hs[j] = f2bf(v);
    float u = aggp[j] * invp + b_p[cb + j];
    hp[j] = f2bf(u);
  }
  *(u16x8*)(A2s + (size_t)n * LDA2 + cb) = hs;
  *(u16x8*)(A2p + (size_t)n * LDA2 + cb) = hp;
}

// ---------------- layer-2 edge agg + epilogue: interleaved C2, depth-2 pipeline ----

__global__ __launch_bounds__(256)
void edge_agg2(const float* __restrict__ C2,
               const int* __restrict__ row_ptr, const int* __restrict__ csr_src,
               const float* __restrict__ att_s, const float* __restrict__ att_p,
               const float* __restrict__ b_s, const float* __restrict__ b_p,
               float* __restrict__ out) {
  int n = (blockIdx.x * 256 + threadIdx.x) >> 6;
  if (n >= NN) return;
  int lane = threadIdx.x & 63;
  float xrs = C2[(size_t)n * 256 + 64 + lane];
  float xrp = C2[(size_t)n * 256 + 192 + lane];
  float ats = att_s[lane], atp = att_p[lane];
  float Ms = -1e30f, Ss = 0.f, ags = 0.f;
  float Mp = -1e30f, Sp = 0.f, agp = 0.f;
  int p0 = row_ptr[n], pe = row_ptr[n + 1];
  int deg = pe - p0;

  auto compute = [&](float cs, float cp) {
    float t = cs + xrs; t = (t > 0.f) ? t : 0.2f * t;
    float u = cp + xrp; u = (u > 0.f) ? u : 0.2f * u;
    float ps_ = ats * t, pp_ = atp * u;
#pragma unroll
    for (int w = 1; w < 64; w <<= 1) { ps_ += __shfl_xor(ps_, w); pp_ += __shfl_xor(pp_, w); }
    float nms = fmaxf(Ms, ps_);
    float fs = __expf(Ms - nms), ws_ = __expf(ps_ - nms);
    Ss = Ss * fs + ws_; ags = ags * fs + ws_ * cs; Ms = nms;
    float nmp = fmaxf(Mp, pp_);
    float fp = __expf(Mp - nmp), wp_ = __expf(pp_ - nmp);
    Sp = Sp * fp + wp_; agp = agp * fp + wp_ * cp; Mp = nmp;
  };

  float s0c, s0d, s1c, s1d;
  {
    int i0 = csr_src[p0];
    s0c = C2[(size_t)i0 * 256 + lane]; s0d = C2[(size_t)i0 * 256 + 128 + lane];
    if (deg > 1) { int i1 = csr_src[p0 + 1]; s1c = C2[(size_t)i1 * 256 + lane]; s1d = C2[(size_t)i1 * 256 + 128 + lane]; }
  }
  int p = p0;
  for (; p + 3 < pe; p += 2) {
    int ia = csr_src[p + 2], ib = csr_src[p + 3];
    float n0c = C2[(size_t)ia * 256 + lane], n0d = C2[(size_t)ia * 256 + 128 + lane];
    float n1c = C2[(size_t)ib * 256 + lane], n1d = C2[(size_t)ib * 256 + 128 + lane];
    compute(s0c, s0d);
    compute(s1c, s1d);
    s0c = n0c; s0d = n0d; s1c = n1c; s1d = n1d;
  }
  int r = pe - p;                                // r in {1,2,3}
  if (r == 3) {
    int i = csr_src[p + 2];
    float tc = C2[(size_t)i * 256 + lane], td = C2[(size_t)i * 256 + 128 + lane];
    compute(s0c, s0d); compute(s1c, s1d); compute(tc, td);
  } else if (r == 2) {
    compute(s0c, s0d); compute(s1c, s1d);
  } else {
    compute(s0c, s0d);
  }

  float vs = ags / Ss + b_s[lane];
  float vp = agp / Sp + b_p[lane];
  if (lane < 32) {
    out[(size_t)n * 64 + lane] = vs;
    out[(size_t)n * 64 + 32 + lane] = vp;
  } else {
    float sps = fmaxf(vs, 0.f) + log1pf(__expf(-fabsf(vs))) + 1e-6f;
    float spp = fmaxf(vp, 0.f) + log1pf(__expf(-fabsf(vp))) + 1e-6f;
    out[(size_t)MU_SZ + n * 64 + (lane - 32)] = sps;
    out[(size_t)MU_SZ + n * 64 + 32 + (lane - 32)] = spp;
  }
}

// ---------------- host ----------------

extern "C" void kernel_launch(void* const* d_in, const int* in_sizes, int n_in,
                              void* d_out, int out_size, void* d_ws, size_t ws_size,
                              hipStream_t stream) {
  const float* x      = (const float*)d_in[0];
  const int*   ei     = (const int*)d_in[1];
  const float* Wl_s1  = (const float*)d_in[2];
  const float* Wr_s1  = (const float*)d_in[3];
  const float* att_s1 = (const float*)d_in[4];
  const float* b_s1   = (const float*)d_in[5];
  const float* Wl_s2  = (const float*)d_in[6];
  const float* Wr_s2  = (const float*)d_in[7];
  const float* att_s2 = (const float*)d_in[8];
  const float* b_s2   = (const float*)d_in[9];
  const float* Wl_p1  = (const float*)d_in[10];
  const float* Wr_p1  = (const float*)d_in[11];
  const float* att_p1 = (const float*)d_in[12];
  const float* b_p1   = (const float*)d_in[13];
  const float* Wl_p2  = (const float*)d_in[14];
  const float* Wr_p2  = (const float*)d_in[15];
  const float* att_p2 = (const float*)d_in[16];
  const float* b_p2   = (const float*)d_in[17];

  char* ws = (char*)d_ws;
  unsigned short* Xb   = (unsigned short*)(ws + 0);           // 20224*3072*2 = 124,256,256
  unsigned short* A2s  = (unsigned short*)(ws + 0);           // 20,578,304 (after Xb dead)
  unsigned short* A2p  = (unsigned short*)(ws + 20578304);    // 20,578,304
  float*          C2   = (float*)(ws + 41156608);             // 20000*256*4 = 20,480,000
  unsigned short* B2s  = (unsigned short*)(ws + 61636608);    // 131,072 (aliases Xb; written post-gemm256)
  unsigned short* B2p  = (unsigned short*)(ws + 61767680);    // 131,072
  unsigned short* Wp   = (unsigned short*)(ws + 124256256);   // 12,582,912
  unsigned short* XL1  = (unsigned short*)(ws + 136839168);   // 20224*2048*2 = 82,837,504
  int* counts  = (int*)(ws + 219676672);                      // 80,000
  int* row_ptr = (int*)(ws + 219836672);                      // 80,004
  int* csr_src = (int*)(ws + 219916688);                      // 1,360,000

  hipMemsetAsync(counts, 0, NN * sizeof(int), stream);

  // W order gives XL1 = [xl_s | xl_p | xr_s | xr_p]
  k_prep<<<PB_CVT, 256, 0, stream>>>(x, Xb, Wl_s1, Wl_p1, Wr_s1, Wr_p1, Wp, ei, counts);

  k_scan<<<1, 1024, 0, stream>>>(counts, row_ptr);

  // gemm256 tiles (0..631) + CSR scatter tail blocks (632..1296)
  gemm256<<<G_TOT, 512, 0, stream>>>(Xb, Wp, XL1, ei, row_ptr, counts, csr_src);

  // edge agg1 (0..4999) + pack_w2b tail (5000..5511)
  edge_agg1<<<AG1_TOT, 256, 0, stream>>>(XL1, row_ptr, csr_src, att_s1, att_p1, b_s1, b_p1,
                                         A2s, A2p, Wl_s2, Wr_s2, Wl_p2, Wr_p2, B2s, B2p);

  gemm_l2<<<dim3(157, 2), 256, 0, stream>>>(A2s, B2s, A2p, B2p, C2);

  edge_agg2<<<5000, 256, 0, stream>>>(C2, row_ptr, csr_src, att_s2, att_p2, b_s2, b_p2, (float*)d_out);
}